// Round 5
// baseline (308.774 us; speedup 1.0000x reference)
//
#include <hip/hip_runtime.h>
#include <math.h>

// Problem constants
#define LBATCH 4096  // tokens per mamba batch (b=2)
#define DM 768
#define RR 192
#define DI 384
#define DSTATE 16
#define DTRANK 12

typedef __attribute__((ext_vector_type(8))) short s16x8;   // 8 bf16 in 4 VGPRs
typedef __attribute__((ext_vector_type(4))) float f32x4;   // MFMA accumulator

__device__ __forceinline__ float silu_f(float x) { return x / (1.f + __expf(-x)); }
__device__ __forceinline__ float softplus_f(float x) { return x > 20.f ? x : log1pf(__expf(x)); }

__device__ __forceinline__ unsigned short f2bf(float f) {   // RNE fp32->bf16
    unsigned u = __float_as_uint(f);
    u += 0x7FFFu + ((u >> 16) & 1u);
    return (unsigned short)(u >> 16);
}

// DPP partial sums across aligned lane groups (VALU pipe, no LDS).
template <int CTRL>
__device__ __forceinline__ float dpp_add(float x) {
    const int y = __builtin_amdgcn_update_dpp(0, __float_as_int(x), CTRL, 0xF, 0xF, false);
    return x + __int_as_float(y);
}

// ---------------------------------------------------------------------------
// Cast all 4 weight matrices fp32->bf16 in one launch. blockIdx.y = tensor.
// ---------------------------------------------------------------------------
__global__ __launch_bounds__(256) void cast_w4(const float* __restrict__ w0,
                                               const float* __restrict__ w1,
                                               const float* __restrict__ w2,
                                               const float* __restrict__ w3,
                                               unsigned short* __restrict__ o0,
                                               unsigned short* __restrict__ o1,
                                               unsigned short* __restrict__ o2,
                                               unsigned short* __restrict__ o3)
{
    const int which = blockIdx.y;
    const float* src = which == 0 ? w0 : which == 1 ? w1 : which == 2 ? w2 : w3;
    unsigned short* dst = which == 0 ? o0 : which == 1 ? o1 : which == 2 ? o2 : o3;
    const int n4 = (which == 2) ? 18432 : 36864;
    const int i = blockIdx.x * 256 + threadIdx.x;
    if (i < n4) {
        const float4 v = ((const float4*)src)[i];
        ushort4 o;
        o.x = f2bf(v.x); o.y = f2bf(v.y); o.z = f2bf(v.z); o.w = f2bf(v.w);
        ((ushort4*)dst)[i] = o;
    }
}

// ---------------------------------------------------------------------------
// bf16 MFMA GEMM: C(M,N) = A(M,K) @ W(N,K)^T, 64x64 tile, 4 waves (wave: 64Mx16N)
// CVT: A is fp32, converted to bf16 during LDS staging.
// MODE 0: store C as bf16 row-major
// MODE 1: transposed split store -> fp32 xi_col[b][ch][t] / z_col[b][ch][t]
// MODE 2: store fp32 C = acc + X (residual), row-major
// ---------------------------------------------------------------------------
template <int MODE, bool CVT>
__global__ __launch_bounds__(256) void gemm_mfma(const void* __restrict__ Araw,
                                                 const unsigned short* __restrict__ W,
                                                 void* __restrict__ C0,
                                                 void* __restrict__ C1,
                                                 const float* __restrict__ X,
                                                 int K, int N)
{
    __shared__ unsigned short As[64 * 40];
    __shared__ unsigned short Ws[64 * 40];
    __shared__ float sC[(MODE == 1) ? 64 * 65 : 1];

    const int tid = threadIdx.x;
    const int wave = tid >> 6, lane = tid & 63;
    const int quad = lane >> 4, l16 = lane & 15;
    const int m0 = blockIdx.y * 64, n0 = blockIdx.x * 64;

    f32x4 acc[4] = {};

    const int sr = tid >> 2;          // staging row 0..63
    const int sc = (tid & 3) * 8;     // staging k-offset
    const unsigned short* Wp = W + (size_t)(n0 + sr) * K + sc;

    for (int k0 = 0; k0 < K; k0 += 32) {
        s16x8 av;
        if (CVT) {
            const float* Af = (const float*)Araw + (size_t)(m0 + sr) * K + sc;
            const float4 f0 = *(const float4*)(Af + k0);
            const float4 f1 = *(const float4*)(Af + k0 + 4);
            union { s16x8 v; unsigned short u[8]; } pk;
            pk.u[0] = f2bf(f0.x); pk.u[1] = f2bf(f0.y); pk.u[2] = f2bf(f0.z); pk.u[3] = f2bf(f0.w);
            pk.u[4] = f2bf(f1.x); pk.u[5] = f2bf(f1.y); pk.u[6] = f2bf(f1.z); pk.u[7] = f2bf(f1.w);
            av = pk.v;
        } else {
            const unsigned short* Ap = (const unsigned short*)Araw + (size_t)(m0 + sr) * K + sc;
            av = *(const s16x8*)(Ap + k0);
        }
        const s16x8 wv = *(const s16x8*)(Wp + k0);
        __syncthreads();
        *(s16x8*)&As[sr * 40 + sc] = av;
        *(s16x8*)&Ws[sr * 40 + sc] = wv;
        __syncthreads();
        const s16x8 b = *(const s16x8*)&Ws[(wave * 16 + l16) * 40 + quad * 8];
#pragma unroll
        for (int mi = 0; mi < 4; ++mi) {
            const s16x8 a = *(const s16x8*)&As[(mi * 16 + l16) * 40 + quad * 8];
            acc[mi] = __builtin_amdgcn_mfma_f32_16x16x32_bf16(a, b, acc[mi], 0, 0, 0);
        }
    }

    if (MODE == 0) {
        unsigned short* Crow = (unsigned short*)C0;
#pragma unroll
        for (int mi = 0; mi < 4; ++mi)
#pragma unroll
            for (int r = 0; r < 4; ++r)
                Crow[(size_t)(m0 + mi * 16 + quad * 4 + r) * N + n0 + wave * 16 + l16] =
                    f2bf(acc[mi][r]);
    } else if (MODE == 2) {
        float* Co = (float*)C0;
#pragma unroll
        for (int mi = 0; mi < 4; ++mi)
#pragma unroll
            for (int r = 0; r < 4; ++r) {
                const size_t off =
                    (size_t)(m0 + mi * 16 + quad * 4 + r) * N + n0 + wave * 16 + l16;
                Co[off] = acc[mi][r] + X[off];
            }
    } else {
#pragma unroll
        for (int mi = 0; mi < 4; ++mi)
#pragma unroll
            for (int r = 0; r < 4; ++r)
                sC[(wave * 16 + l16) * 65 + mi * 16 + quad * 4 + r] = acc[mi][r];
        __syncthreads();
        const int b = m0 >> 12, tl0 = m0 & 4095;
        for (int idx = tid; idx < 1024; idx += 256) {
            const int nn = idx >> 4, t4 = (idx & 15) << 2;
            const float4 v = make_float4(sC[nn * 65 + t4], sC[nn * 65 + t4 + 1],
                                         sC[nn * 65 + t4 + 2], sC[nn * 65 + t4 + 3]);
            const int gch = n0 + nn;
            float* dst = (gch < DI)
                             ? (float*)C0 + ((size_t)(b * DI + gch)) * LBATCH
                             : (float*)C1 + ((size_t)(b * DI + gch - DI)) * LBATCH;
            *(float4*)(dst + tl0 + t4) = v;
        }
    }
}

// ---------------------------------------------------------------------------
// m = y @ out_proj^T (bf16 MFMA, K=384, N=192) + LayerNorm + exact GELU -> bf16 G.
// A is fp32 y_col [b][d][t]: transposed + cast during LDS staging (fused).
// Tile 64M x 192N; wave = 16M x 192N (LN is wave-local via DPP).
// ---------------------------------------------------------------------------
__global__ __launch_bounds__(256) void gemm_ln_mfma(const float* __restrict__ ycol,
                                                    const unsigned short* __restrict__ Wb,
                                                    const float* __restrict__ lng,
                                                    const float* __restrict__ lnb,
                                                    unsigned short* __restrict__ G)
{
    __shared__ unsigned short As[64 * 40];
    __shared__ unsigned short Ws[192 * 40];
    const int tid = threadIdx.x;
    const int wave = tid >> 6, lane = tid & 63;
    const int quad = lane >> 4, l16 = lane & 15;
    const int m0 = blockIdx.x * 64;
    const int b = m0 >> 12, tl0 = m0 & 4095;

    f32x4 acc[12] = {};
    const int sr = tid >> 2, sc = (tid & 3) * 8;
    // A-staging map: d-pair kd2 = tid>>4 (0..15), token offset tt0 = (tid&15)*4
    const int kd2 = tid >> 4, tt0 = (tid & 15) << 2;

    for (int k0 = 0; k0 < DI; k0 += 32) {
        const float* y0 = ycol + ((size_t)(b * DI + k0 + 2 * kd2)) * LBATCH + tl0 + tt0;
        const float4 v0 = *(const float4*)y0;            // d = k0+2*kd2,   t = tt0..tt0+3
        const float4 v1 = *(const float4*)(y0 + LBATCH); // d = k0+2*kd2+1
        const s16x8 w0 = *(const s16x8*)(Wb + (size_t)sr * DI + k0 + sc);
        const s16x8 w1 = *(const s16x8*)(Wb + (size_t)(sr + 64) * DI + k0 + sc);
        const s16x8 w2 = *(const s16x8*)(Wb + (size_t)(sr + 128) * DI + k0 + sc);
        __syncthreads();
        {
            const float e0[4] = {v0.x, v0.y, v0.z, v0.w};
            const float e1[4] = {v1.x, v1.y, v1.z, v1.w};
#pragma unroll
            for (int r = 0; r < 4; ++r) {
                const unsigned pair =
                    (unsigned)f2bf(e0[r]) | ((unsigned)f2bf(e1[r]) << 16);
                *(unsigned*)&As[(tt0 + r) * 40 + 2 * kd2] = pair;
            }
        }
        *(s16x8*)&Ws[sr * 40 + sc] = w0;
        *(s16x8*)&Ws[(sr + 64) * 40 + sc] = w1;
        *(s16x8*)&Ws[(sr + 128) * 40 + sc] = w2;
        __syncthreads();
        const s16x8 a = *(const s16x8*)&As[(wave * 16 + l16) * 40 + quad * 8];
#pragma unroll
        for (int j = 0; j < 12; ++j) {
            const s16x8 bb = *(const s16x8*)&Ws[(j * 16 + l16) * 40 + quad * 8];
            acc[j] = __builtin_amdgcn_mfma_f32_16x16x32_bf16(a, bb, acc[j], 0, 0, 0);
        }
    }

    // LayerNorm stats per row (row = m0 + wave*16 + quad*4 + r), wave-local via DPP
    float s[4] = {0, 0, 0, 0}, q[4] = {0, 0, 0, 0};
#pragma unroll
    for (int j = 0; j < 12; ++j)
#pragma unroll
        for (int r = 0; r < 4; ++r) {
            s[r] += acc[j][r];
            q[r] = fmaf(acc[j][r], acc[j][r], q[r]);
        }
#pragma unroll
    for (int r = 0; r < 4; ++r) {
        s[r] = dpp_add<0xB1>(s[r]); s[r] = dpp_add<0x4E>(s[r]);
        s[r] = dpp_add<0x124>(s[r]); s[r] = dpp_add<0x128>(s[r]);
        q[r] = dpp_add<0xB1>(q[r]); q[r] = dpp_add<0x4E>(q[r]);
        q[r] = dpp_add<0x124>(q[r]); q[r] = dpp_add<0x128>(q[r]);
    }
    float mu[4], rs[4];
#pragma unroll
    for (int r = 0; r < 4; ++r) {
        mu[r] = s[r] * (1.f / 192.f);
        const float var = q[r] * (1.f / 192.f) - mu[r] * mu[r];
        rs[r] = rsqrtf(var + 1e-5f);
    }
    float gv[12], bv[12];
#pragma unroll
    for (int j = 0; j < 12; ++j) { gv[j] = lng[j * 16 + l16]; bv[j] = lnb[j * 16 + l16]; }
#pragma unroll
    for (int j = 0; j < 12; ++j)
#pragma unroll
        for (int r = 0; r < 4; ++r) {
            const float v = (acc[j][r] - mu[r]) * rs[r] * gv[j] + bv[j];
            const float ge = 0.5f * v * (1.f + erff(v * 0.70710678118654752f));
            G[(size_t)(m0 + wave * 16 + quad * 4 + r) * RR + j * 16 + l16] = f2bf(ge);
        }
}

// ---------------------------------------------------------------------------
// Depthwise causal conv (width 4) + SiLU.  One block per (b, channel) row.
// ---------------------------------------------------------------------------
__global__ __launch_bounds__(256) void conv_silu_kernel(const float* __restrict__ xi_col,
                                                        const float* __restrict__ cw,
                                                        const float* __restrict__ cb,
                                                        float* __restrict__ u_col)
{
    const int row = blockIdx.x;      // b*384 + c
    const int c = row % DI;
    const float* xp = xi_col + (size_t)row * LBATCH;
    float* up = u_col + (size_t)row * LBATCH;
    const float w0 = cw[c * 4 + 0], w1 = cw[c * 4 + 1], w2 = cw[c * 4 + 2], w3 = cw[c * 4 + 3];
    const float bb = cb[c];
    for (int t = threadIdx.x; t < LBATCH; t += 256) {
        const float x3 = xp[t];
        const float x2 = (t >= 1) ? xp[t - 1] : 0.f;
        const float x1 = (t >= 2) ? xp[t - 2] : 0.f;
        const float x0 = (t >= 3) ? xp[t - 3] : 0.f;
        const float v = bb + w0 * x0 + w1 * x1 + w2 * x2 + w3 * x3;
        up[t] = silu_f(v);
    }
}

// ---------------------------------------------------------------------------
// FUSED: x_dbl = u @ x_proj^T (N=44, K=384) AND delta = softplus(dt@dtw^T+b).
// A read col-major (u_col). Outputs: BCt interleaved [b][t][32], delta_col
// [b][d][t].  dt never leaves the block (stays in sC).
// ---------------------------------------------------------------------------
__global__ __launch_bounds__(256) void xdbl_delta_kernel(const float* __restrict__ u_col,
                                                         const float* __restrict__ Wx,
                                                         const float* __restrict__ dtw,
                                                         const float* __restrict__ dtb,
                                                         float* __restrict__ BCt,
                                                         float* __restrict__ delta_col)
{
    __shared__ float As[16][68];
    __shared__ float Bs[16][68];
    __shared__ float sC[64 * 69];
    __shared__ float sdtw[DI * DTRANK];   // 4608 floats
    const int tid = threadIdx.x;
    const int ty = tid >> 4, tx = tid & 15;
    const int m0 = blockIdx.x * 64;
    const int b = m0 >> 12, tl0 = m0 & 4095;

    for (int idx = tid; idx < DI * DTRANK; idx += 256) sdtw[idx] = dtw[idx];

    float acc[4][4];
#pragma unroll
    for (int i = 0; i < 4; ++i)
#pragma unroll
        for (int j = 0; j < 4; ++j) acc[i][j] = 0.f;

    for (int k0 = 0; k0 < DI; k0 += 16) {
        __syncthreads();
        {
            const int m = tid & 63;
            const int kk0 = tid >> 6;
#pragma unroll
            for (int r = 0; r < 4; ++r)
                As[kk0 + 4 * r][m] =
                    u_col[((size_t)(b * DI + k0 + kk0 + 4 * r)) * LBATCH + tl0 + m];
        }
        if (tid < 176) {
            const int n = tid >> 2;
            const int lk2 = (tid & 3) << 2;
            const float4 wv = *(const float4*)(Wx + (size_t)n * DI + k0 + lk2);
            Bs[lk2 + 0][n] = wv.x; Bs[lk2 + 1][n] = wv.y; Bs[lk2 + 2][n] = wv.z; Bs[lk2 + 3][n] = wv.w;
        }
        __syncthreads();
#pragma unroll
        for (int kk = 0; kk < 16; ++kk) {
            const float4 a4 = *(const float4*)&As[kk][ty << 2];
            const float4 b4 = *(const float4*)&Bs[kk][tx << 2];
            const float aa[4] = {a4.x, a4.y, a4.z, a4.w};
            const float bb[4] = {b4.x, b4.y, b4.z, b4.w};
#pragma unroll
            for (int i = 0; i < 4; ++i)
#pragma unroll
                for (int j = 0; j < 4; ++j)
                    acc[i][j] = fmaf(aa[i], bb[j], acc[i][j]);
        }
    }
    __syncthreads();
#pragma unroll
    for (int i = 0; i < 4; ++i)
#pragma unroll
        for (int j = 0; j < 4; ++j)
            sC[((ty << 2) + i) * 69 + (tx << 2) + j] = acc[i][j];
    __syncthreads();
    // BCt: cols 12..43
    for (int idx = tid; idx < 64 * 32; idx += 256) {
        const int t = idx >> 5, c = idx & 31;
        BCt[((size_t)(b * LBATCH + tl0 + t)) * 32 + c] = sC[t * 69 + DTRANK + c];
    }
    // delta: thread (tl = tid&63 token, dgrp = tid>>6), d strides of 4
    {
        const int tl = tid & 63;
        const int dgrp = tid >> 6;
        float dtv[DTRANK];
#pragma unroll
        for (int r = 0; r < DTRANK; ++r) dtv[r] = sC[tl * 69 + r];
        for (int d = dgrp; d < DI; d += 4) {
            float a = dtb[d];
#pragma unroll
            for (int r = 0; r < DTRANK; ++r)
                a = fmaf(dtv[r], sdtw[d * DTRANK + r], a);
            delta_col[((size_t)(b * DI + d)) * LBATCH + tl0 + tl] = softplus_f(a);
        }
    }
}

// ---------------------------------------------------------------------------
// Selective scan v4: 512 threads/block, 128 segments x 32 steps, 4 states/thread.
// Thread (s = tid>>2 in 0..127, n4 = tid&3): segment s, states 4n4..4n4+3.
// Middle: 8 waves x 2 states; 64-lane scan per segment-half + affine stitch.
// ---------------------------------------------------------------------------
__global__ __launch_bounds__(512) void scan_kernel(const float* __restrict__ delta_col,
                                                   const float* __restrict__ u_col,
                                                   const float* __restrict__ BCt,
                                                   const float* __restrict__ z_col,
                                                   const float* __restrict__ A_log,
                                                   const float* __restrict__ Dv,
                                                   float* __restrict__ y_col)
{
    const int bd = blockIdx.x;       // b*384 + d
    const int b = bd / DI;
    const int d = bd - b * DI;
    const int tid = threadIdx.x;
    const int n4 = tid & 3;          // state quad (states 4n4..4n4+3)
    const int s = tid >> 2;          // segment 0..127

    const float4 al = *(const float4*)(A_log + d * DSTATE + 4 * n4);
    // An2[q] = -exp(A_log) * log2(e)  -> a = exp2(delta * An2)
    float An2[4];
    An2[0] = -__expf(al.x) * 1.44269504f;
    An2[1] = -__expf(al.y) * 1.44269504f;
    An2[2] = -__expf(al.z) * 1.44269504f;
    An2[3] = -__expf(al.w) * 1.44269504f;
    const float Dd = Dv[d];

    const int t0 = s * 32;
    const float* dp = delta_col + (size_t)bd * LBATCH + t0;
    const float* up = u_col + (size_t)bd * LBATCH + t0;
    const float* zp = z_col + (size_t)bd * LBATCH + t0;
    const float* bc = BCt + ((size_t)b * LBATCH + t0) * 32 + 4 * n4;
    float* yp = y_col + (size_t)bd * LBATCH + t0;

    __shared__ float aggA[128 * 20];
    __shared__ float aggB[128 * 20];
    __shared__ float hst[128 * 20];

    // ---- phase 1: segment affine aggregate for 4 states (32 steps) ----
    float Ag[4] = {1.f, 1.f, 1.f, 1.f}, Bg[4] = {0.f, 0.f, 0.f, 0.f};
    {
        const float* bci = bc;
        for (int i = 0; i < 32; i += 4) {
            const float4 d4 = *(const float4*)(dp + i);
            const float4 u4 = *(const float4*)(up + i);
            const float dls[4] = {d4.x, d4.y, d4.z, d4.w};
            const float uus[4] = {u4.x, u4.y, u4.z, u4.w};
#pragma unroll
            for (int j = 0; j < 4; ++j) {
                const float4 bm4 = *(const float4*)(bci + j * 32);
                const float du = dls[j] * uus[j];
                const float bms[4] = {bm4.x, bm4.y, bm4.z, bm4.w};
#pragma unroll
                for (int q = 0; q < 4; ++q) {
                    const float a = exp2f(dls[j] * An2[q]);
                    Bg[q] = fmaf(a, Bg[q], du * bms[q]);
                    Ag[q] *= a;
                }
            }
            bci += 128;
        }
    }
    *(float4*)&aggA[s * 20 + 4 * n4] = make_float4(Ag[0], Ag[1], Ag[2], Ag[3]);
    *(float4*)&aggB[s * 20 + 4 * n4] = make_float4(Bg[0], Bg[1], Bg[2], Bg[3]);
    __syncthreads();

    // ---- middle: per-state inclusive scan over 128 segment aggregates ----
    {
        const int w = tid >> 6;      // wave 0..7 -> states 2w, 2w+1
        const int lane = tid & 63;
#pragma unroll
        for (int r = 0; r < 2; ++r) {
            const int n = w * 2 + r;
            // first half: segments 0..63
            float sA = aggA[lane * 20 + n];
            float sB = aggB[lane * 20 + n];
#pragma unroll
            for (int o = 1; o < 64; o <<= 1) {
                const float pA = __shfl_up(sA, (unsigned)o, 64);
                const float pB = __shfl_up(sB, (unsigned)o, 64);
                if (lane >= o) { sB = fmaf(sA, pB, sB); sA *= pA; }
            }
            const float B0tot = __shfl(sB, 63, 64);
            const float ex0 = __shfl_up(sB, 1, 64);
            hst[lane * 20 + n] = (lane == 0) ? 0.f : ex0;
            // second half: segments 64..127, stitched with half-0 total
            float tA = aggA[(64 + lane) * 20 + n];
            float tB = aggB[(64 + lane) * 20 + n];
#pragma unroll
            for (int o = 1; o < 64; o <<= 1) {
                const float pA = __shfl_up(tA, (unsigned)o, 64);
                const float pB = __shfl_up(tB, (unsigned)o, 64);
                if (lane >= o) { tB = fmaf(tA, pB, tB); tA *= pA; }
            }
            const float exA = (lane == 0) ? 1.f : __shfl_up(tA, 1, 64);
            const float exB = (lane == 0) ? 0.f : __shfl_up(tB, 1, 64);
            hst[(64 + lane) * 20 + n] = fmaf(exA, B0tot, exB);
        }
    }
    __syncthreads();

    // ---- phase 2: replay with exact incoming state ----
    const float4 h4 = *(const float4*)&hst[s * 20 + 4 * n4];
    float h[4] = {h4.x, h4.y, h4.z, h4.w};
    {
        const float* bci = bc;
        for (int i = 0; i < 32; i += 4) {
            const float4 d4 = *(const float4*)(dp + i);
            const float4 u4 = *(const float4*)(up + i);
            const float4 z4 = *(const float4*)(zp + i);
            const float dls[4] = {d4.x, d4.y, d4.z, d4.w};
            const float uus[4] = {u4.x, u4.y, u4.z, u4.w};
            const float zzs[4] = {z4.x, z4.y, z4.z, z4.w};
#pragma unroll
            for (int j = 0; j < 4; ++j) {
                const float4 bm4 = *(const float4*)(bci + j * 32);
                const float4 cm4 = *(const float4*)(bci + j * 32 + 16);
                const float du = dls[j] * uus[j];
                const float bms[4] = {bm4.x, bm4.y, bm4.z, bm4.w};
                const float cms[4] = {cm4.x, cm4.y, cm4.z, cm4.w};
                float p = 0.f;
#pragma unroll
                for (int q = 0; q < 4; ++q) {
                    const float a = exp2f(dls[j] * An2[q]);
                    h[q] = fmaf(a, h[q], du * bms[q]);
                    p = fmaf(h[q], cms[q], p);
                }
                p = dpp_add<0xB1>(p);   // quad xor1
                p = dpp_add<0x4E>(p);   // quad xor2
                if (n4 == 0)
                    yp[i + j] = (p + uus[j] * Dd) * silu_f(zzs[j]);
            }
            bci += 128;
        }
    }
}

// ---------------------------------------------------------------------------
extern "C" void kernel_launch(void* const* d_in, const int* in_sizes, int n_in,
                              void* d_out, int out_size, void* d_ws, size_t ws_size,
                              hipStream_t stream)
{
    const float* x         = (const float*)d_in[0];
    const float* down_w    = (const float*)d_in[1];
    const float* up_w      = (const float*)d_in[2];
    const float* in_proj_w = (const float*)d_in[3];
    const float* conv_w    = (const float*)d_in[4];
    const float* conv_b    = (const float*)d_in[5];
    const float* x_proj_w  = (const float*)d_in[6];
    const float* dt_proj_w = (const float*)d_in[7];
    const float* dt_proj_b = (const float*)d_in[8];
    const float* A_log     = (const float*)d_in[9];
    const float* D_ssm     = (const float*)d_in[10];
    const float* out_proj_w= (const float*)d_in[11];
    const float* ln_g      = (const float*)d_in[12];
    const float* ln_b      = (const float*)d_in[13];
    float* out = (float*)d_out;
    float* ws = (float*)d_ws;

    // fp32 workspace
    float* xi_col    = ws;                        // 2*384*4096 = 3145728
    float* z_col     = xi_col + 3145728;          // 3145728
    float* u_col     = z_col + 3145728;           // 3145728
    float* y_col     = u_col + 3145728;           // 3145728
    float* BCt       = y_col + 3145728;           // 262144
    float* delta_col = xi_col;                    // alias: xi dead after conv
    // bf16 workspace
    unsigned short* xdb    = (unsigned short*)(BCt + 262144);  // 1572864
    unsigned short* gb     = xdb;                 // alias: xdb dead after gemm2
    unsigned short* wdownb = xdb + 1572864;       // 147456
    unsigned short* winb   = wdownb + 147456;     // 147456
    unsigned short* woutb  = winb + 147456;       // 73728
    unsigned short* wupb   = woutb + 73728;       // 147456

    // 0. all weight casts in one launch
    cast_w4<<<dim3(144, 4), 256, 0, stream>>>(down_w, in_proj_w, out_proj_w, up_w,
                                              wdownb, winb, woutb, wupb);
    // 1. xd = x @ down_w^T  (fp32 A converted in staging) -> xdb bf16 row-major
    gemm_mfma<0, true><<<dim3(3, 128), 256, 0, stream>>>(x, wdownb, xdb, nullptr, nullptr, DM, RR);
    // 2. xz = xd @ in_proj^T -> xi_col, z_col (fp32 col-major)
    gemm_mfma<1, false><<<dim3(12, 128), 256, 0, stream>>>(xdb, winb, xi_col, z_col, nullptr, RR, 2 * DI);
    // 3. depthwise conv4 + silu -> u_col
    conv_silu_kernel<<<768, 256, 0, stream>>>(xi_col, conv_w, conv_b, u_col);
    // 4. fused x_dbl + delta -> BCt, delta_col (aliases xi_col)
    xdbl_delta_kernel<<<128, 256, 0, stream>>>(u_col, x_proj_w, dt_proj_w, dt_proj_b,
                                               BCt, delta_col);
    // 5. selective scan v4 + gating -> y_col
    scan_kernel<<<768, 512, 0, stream>>>(delta_col, u_col, BCt, z_col, A_log, D_ssm, y_col);
    // 6. m = y @ out_proj^T + LN + GELU (transpose fused in staging) -> gb
    gemm_ln_mfma<<<128, 256, 0, stream>>>(y_col, woutb, ln_g, ln_b, gb);
    // 7. out = x + g @ up_w^T (fp32 store)
    gemm_mfma<2, false><<<dim3(12, 128), 256, 0, stream>>>(gb, wupb, out, nullptr, x, RR, DM);
}

// Round 6
// 285.331 us; speedup vs baseline: 1.0822x; 1.0822x over previous
//
#include <hip/hip_runtime.h>
#include <math.h>

// Problem constants
#define LBATCH 4096  // tokens per mamba batch (b=2)
#define DM 768
#define RR 192
#define DI 384
#define DSTATE 16
#define DTRANK 12

typedef __attribute__((ext_vector_type(8))) short s16x8;   // 8 bf16 in 4 VGPRs
typedef __attribute__((ext_vector_type(4))) float f32x4;   // MFMA accumulator

__device__ __forceinline__ float silu_f(float x) { return x / (1.f + __expf(-x)); }
__device__ __forceinline__ float softplus_f(float x) { return x > 20.f ? x : log1pf(__expf(x)); }

__device__ __forceinline__ unsigned short f2bf(float f) {   // RNE fp32->bf16
    unsigned u = __float_as_uint(f);
    u += 0x7FFFu + ((u >> 16) & 1u);
    return (unsigned short)(u >> 16);
}

// DPP partial sums across aligned lane groups (VALU pipe, no LDS).
template <int CTRL>
__device__ __forceinline__ float dpp_add(float x) {
    const int y = __builtin_amdgcn_update_dpp(0, __float_as_int(x), CTRL, 0xF, 0xF, false);
    return x + __int_as_float(y);
}

// ---------------------------------------------------------------------------
// Cast all 4 weight matrices fp32->bf16 in one launch. blockIdx.y = tensor.
// ---------------------------------------------------------------------------
__global__ __launch_bounds__(256) void cast_w4(const float* __restrict__ w0,
                                               const float* __restrict__ w1,
                                               const float* __restrict__ w2,
                                               const float* __restrict__ w3,
                                               unsigned short* __restrict__ o0,
                                               unsigned short* __restrict__ o1,
                                               unsigned short* __restrict__ o2,
                                               unsigned short* __restrict__ o3)
{
    const int which = blockIdx.y;
    const float* src = which == 0 ? w0 : which == 1 ? w1 : which == 2 ? w2 : w3;
    unsigned short* dst = which == 0 ? o0 : which == 1 ? o1 : which == 2 ? o2 : o3;
    const int n4 = (which == 2) ? 18432 : 36864;
    const int i = blockIdx.x * 256 + threadIdx.x;
    if (i < n4) {
        const float4 v = ((const float4*)src)[i];
        ushort4 o;
        o.x = f2bf(v.x); o.y = f2bf(v.y); o.z = f2bf(v.z); o.w = f2bf(v.w);
        ((ushort4*)dst)[i] = o;
    }
}

// ---------------------------------------------------------------------------
// bf16 MFMA GEMM: C(M,N) = A(M,K) @ W(N,K)^T, 64x64 tile, 4 waves (wave: 64Mx16N)
// CVT: A is fp32, converted to bf16 during LDS staging.
// MODE 0: store C as bf16 row-major
// MODE 1: transposed split store -> fp32 xi_col[b][ch][t] / z_col[b][ch][t]
// MODE 2: store fp32 C = acc + X (residual), row-major
// ---------------------------------------------------------------------------
template <int MODE, bool CVT>
__global__ __launch_bounds__(256) void gemm_mfma(const void* __restrict__ Araw,
                                                 const unsigned short* __restrict__ W,
                                                 void* __restrict__ C0,
                                                 void* __restrict__ C1,
                                                 const float* __restrict__ X,
                                                 int K, int N)
{
    __shared__ unsigned short As[64 * 40];
    __shared__ unsigned short Ws[64 * 40];
    __shared__ float sC[(MODE == 1) ? 64 * 65 : 1];

    const int tid = threadIdx.x;
    const int wave = tid >> 6, lane = tid & 63;
    const int quad = lane >> 4, l16 = lane & 15;
    const int m0 = blockIdx.y * 64, n0 = blockIdx.x * 64;

    f32x4 acc[4] = {};

    const int sr = tid >> 2;          // staging row 0..63
    const int sc = (tid & 3) * 8;     // staging k-offset
    const unsigned short* Wp = W + (size_t)(n0 + sr) * K + sc;

    for (int k0 = 0; k0 < K; k0 += 32) {
        s16x8 av;
        if (CVT) {
            const float* Af = (const float*)Araw + (size_t)(m0 + sr) * K + sc;
            const float4 f0 = *(const float4*)(Af + k0);
            const float4 f1 = *(const float4*)(Af + k0 + 4);
            union { s16x8 v; unsigned short u[8]; } pk;
            pk.u[0] = f2bf(f0.x); pk.u[1] = f2bf(f0.y); pk.u[2] = f2bf(f0.z); pk.u[3] = f2bf(f0.w);
            pk.u[4] = f2bf(f1.x); pk.u[5] = f2bf(f1.y); pk.u[6] = f2bf(f1.z); pk.u[7] = f2bf(f1.w);
            av = pk.v;
        } else {
            const unsigned short* Ap = (const unsigned short*)Araw + (size_t)(m0 + sr) * K + sc;
            av = *(const s16x8*)(Ap + k0);
        }
        const s16x8 wv = *(const s16x8*)(Wp + k0);
        __syncthreads();
        *(s16x8*)&As[sr * 40 + sc] = av;
        *(s16x8*)&Ws[sr * 40 + sc] = wv;
        __syncthreads();
        const s16x8 b = *(const s16x8*)&Ws[(wave * 16 + l16) * 40 + quad * 8];
#pragma unroll
        for (int mi = 0; mi < 4; ++mi) {
            const s16x8 a = *(const s16x8*)&As[(mi * 16 + l16) * 40 + quad * 8];
            acc[mi] = __builtin_amdgcn_mfma_f32_16x16x32_bf16(a, b, acc[mi], 0, 0, 0);
        }
    }

    if (MODE == 0) {
        unsigned short* Crow = (unsigned short*)C0;
#pragma unroll
        for (int mi = 0; mi < 4; ++mi)
#pragma unroll
            for (int r = 0; r < 4; ++r)
                Crow[(size_t)(m0 + mi * 16 + quad * 4 + r) * N + n0 + wave * 16 + l16] =
                    f2bf(acc[mi][r]);
    } else if (MODE == 2) {
        float* Co = (float*)C0;
#pragma unroll
        for (int mi = 0; mi < 4; ++mi)
#pragma unroll
            for (int r = 0; r < 4; ++r) {
                const size_t off =
                    (size_t)(m0 + mi * 16 + quad * 4 + r) * N + n0 + wave * 16 + l16;
                Co[off] = acc[mi][r] + X[off];
            }
    } else {
#pragma unroll
        for (int mi = 0; mi < 4; ++mi)
#pragma unroll
            for (int r = 0; r < 4; ++r)
                sC[(wave * 16 + l16) * 65 + mi * 16 + quad * 4 + r] = acc[mi][r];
        __syncthreads();
        const int b = m0 >> 12, tl0 = m0 & 4095;
        for (int idx = tid; idx < 1024; idx += 256) {
            const int nn = idx >> 4, t4 = (idx & 15) << 2;
            const float4 v = make_float4(sC[nn * 65 + t4], sC[nn * 65 + t4 + 1],
                                         sC[nn * 65 + t4 + 2], sC[nn * 65 + t4 + 3]);
            const int gch = n0 + nn;
            float* dst = (gch < DI)
                             ? (float*)C0 + ((size_t)(b * DI + gch)) * LBATCH
                             : (float*)C1 + ((size_t)(b * DI + gch - DI)) * LBATCH;
            *(float4*)(dst + tl0 + t4) = v;
        }
    }
}

// ---------------------------------------------------------------------------
// m = y @ out_proj^T (bf16 MFMA, K=384, N=192) + LayerNorm + exact GELU -> bf16 G.
// A is fp32 y_col [b][d][t]: transposed + cast during LDS staging (fused).
// Tile 64M x 192N; wave = 16M x 192N (LN is wave-local via DPP).
// ---------------------------------------------------------------------------
__global__ __launch_bounds__(256) void gemm_ln_mfma(const float* __restrict__ ycol,
                                                    const unsigned short* __restrict__ Wb,
                                                    const float* __restrict__ lng,
                                                    const float* __restrict__ lnb,
                                                    unsigned short* __restrict__ G)
{
    __shared__ unsigned short As[64 * 40];
    __shared__ unsigned short Ws[192 * 40];
    const int tid = threadIdx.x;
    const int wave = tid >> 6, lane = tid & 63;
    const int quad = lane >> 4, l16 = lane & 15;
    const int m0 = blockIdx.x * 64;
    const int b = m0 >> 12, tl0 = m0 & 4095;

    f32x4 acc[12] = {};
    const int sr = tid >> 2, sc = (tid & 3) * 8;
    // A-staging map: d-pair kd2 = tid>>4 (0..15), token offset tt0 = (tid&15)*4
    const int kd2 = tid >> 4, tt0 = (tid & 15) << 2;

    for (int k0 = 0; k0 < DI; k0 += 32) {
        const float* y0 = ycol + ((size_t)(b * DI + k0 + 2 * kd2)) * LBATCH + tl0 + tt0;
        const float4 v0 = *(const float4*)y0;            // d = k0+2*kd2,   t = tt0..tt0+3
        const float4 v1 = *(const float4*)(y0 + LBATCH); // d = k0+2*kd2+1
        const s16x8 w0 = *(const s16x8*)(Wb + (size_t)sr * DI + k0 + sc);
        const s16x8 w1 = *(const s16x8*)(Wb + (size_t)(sr + 64) * DI + k0 + sc);
        const s16x8 w2 = *(const s16x8*)(Wb + (size_t)(sr + 128) * DI + k0 + sc);
        __syncthreads();
        {
            const float e0[4] = {v0.x, v0.y, v0.z, v0.w};
            const float e1[4] = {v1.x, v1.y, v1.z, v1.w};
#pragma unroll
            for (int r = 0; r < 4; ++r) {
                const unsigned pair =
                    (unsigned)f2bf(e0[r]) | ((unsigned)f2bf(e1[r]) << 16);
                *(unsigned*)&As[(tt0 + r) * 40 + 2 * kd2] = pair;
            }
        }
        *(s16x8*)&Ws[sr * 40 + sc] = w0;
        *(s16x8*)&Ws[(sr + 64) * 40 + sc] = w1;
        *(s16x8*)&Ws[(sr + 128) * 40 + sc] = w2;
        __syncthreads();
        const s16x8 a = *(const s16x8*)&As[(wave * 16 + l16) * 40 + quad * 8];
#pragma unroll
        for (int j = 0; j < 12; ++j) {
            const s16x8 bb = *(const s16x8*)&Ws[(j * 16 + l16) * 40 + quad * 8];
            acc[j] = __builtin_amdgcn_mfma_f32_16x16x32_bf16(a, bb, acc[j], 0, 0, 0);
        }
    }

    // LayerNorm stats per row (row = m0 + wave*16 + quad*4 + r), wave-local via DPP
    float s[4] = {0, 0, 0, 0}, q[4] = {0, 0, 0, 0};
#pragma unroll
    for (int j = 0; j < 12; ++j)
#pragma unroll
        for (int r = 0; r < 4; ++r) {
            s[r] += acc[j][r];
            q[r] = fmaf(acc[j][r], acc[j][r], q[r]);
        }
#pragma unroll
    for (int r = 0; r < 4; ++r) {
        s[r] = dpp_add<0xB1>(s[r]); s[r] = dpp_add<0x4E>(s[r]);
        s[r] = dpp_add<0x124>(s[r]); s[r] = dpp_add<0x128>(s[r]);
        q[r] = dpp_add<0xB1>(q[r]); q[r] = dpp_add<0x4E>(q[r]);
        q[r] = dpp_add<0x124>(q[r]); q[r] = dpp_add<0x128>(q[r]);
    }
    float mu[4], rs[4];
#pragma unroll
    for (int r = 0; r < 4; ++r) {
        mu[r] = s[r] * (1.f / 192.f);
        const float var = q[r] * (1.f / 192.f) - mu[r] * mu[r];
        rs[r] = rsqrtf(var + 1e-5f);
    }
    float gv[12], bv[12];
#pragma unroll
    for (int j = 0; j < 12; ++j) { gv[j] = lng[j * 16 + l16]; bv[j] = lnb[j * 16 + l16]; }
#pragma unroll
    for (int j = 0; j < 12; ++j)
#pragma unroll
        for (int r = 0; r < 4; ++r) {
            const float v = (acc[j][r] - mu[r]) * rs[r] * gv[j] + bv[j];
            const float ge = 0.5f * v * (1.f + erff(v * 0.70710678118654752f));
            G[(size_t)(m0 + wave * 16 + quad * 4 + r) * RR + j * 16 + l16] = f2bf(ge);
        }
}

// ---------------------------------------------------------------------------
// Depthwise causal conv (width 4) + SiLU.  One block per (b, channel) row.
// ---------------------------------------------------------------------------
__global__ __launch_bounds__(256) void conv_silu_kernel(const float* __restrict__ xi_col,
                                                        const float* __restrict__ cw,
                                                        const float* __restrict__ cb,
                                                        float* __restrict__ u_col)
{
    const int row = blockIdx.x;      // b*384 + c
    const int c = row % DI;
    const float* xp = xi_col + (size_t)row * LBATCH;
    float* up = u_col + (size_t)row * LBATCH;
    const float w0 = cw[c * 4 + 0], w1 = cw[c * 4 + 1], w2 = cw[c * 4 + 2], w3 = cw[c * 4 + 3];
    const float bb = cb[c];
    for (int t = threadIdx.x; t < LBATCH; t += 256) {
        const float x3 = xp[t];
        const float x2 = (t >= 1) ? xp[t - 1] : 0.f;
        const float x1 = (t >= 2) ? xp[t - 2] : 0.f;
        const float x0 = (t >= 3) ? xp[t - 3] : 0.f;
        const float v = bb + w0 * x0 + w1 * x1 + w2 * x2 + w3 * x3;
        up[t] = silu_f(v);
    }
}

// ---------------------------------------------------------------------------
// x_dbl = u @ x_proj^T (N=44, K=384), A read col-major (u_col).
// Outputs: dt row-major (8192x12), BCt interleaved [b][t][32] (B 0..15, C 16..31).
// ---------------------------------------------------------------------------
__global__ __launch_bounds__(256) void gemm_xdbl(const float* __restrict__ u_col,
                                                 const float* __restrict__ Wx,
                                                 float* __restrict__ dt,
                                                 float* __restrict__ BCt)
{
    __shared__ float As[16][68];
    __shared__ float Bs[16][68];
    __shared__ float sC[64 * 69];
    const int tid = threadIdx.x;
    const int ty = tid >> 4, tx = tid & 15;
    const int m0 = blockIdx.x * 64;
    const int b = m0 >> 12, tl0 = m0 & 4095;

    float acc[4][4];
#pragma unroll
    for (int i = 0; i < 4; ++i)
#pragma unroll
        for (int j = 0; j < 4; ++j) acc[i][j] = 0.f;

    for (int k0 = 0; k0 < DI; k0 += 16) {
        __syncthreads();
        {
            const int m = tid & 63;
            const int kk0 = tid >> 6;
#pragma unroll
            for (int r = 0; r < 4; ++r)
                As[kk0 + 4 * r][m] =
                    u_col[((size_t)(b * DI + k0 + kk0 + 4 * r)) * LBATCH + tl0 + m];
        }
        if (tid < 176) {
            const int n = tid >> 2;
            const int lk2 = (tid & 3) << 2;
            const float4 wv = *(const float4*)(Wx + (size_t)n * DI + k0 + lk2);
            Bs[lk2 + 0][n] = wv.x; Bs[lk2 + 1][n] = wv.y; Bs[lk2 + 2][n] = wv.z; Bs[lk2 + 3][n] = wv.w;
        }
        __syncthreads();
#pragma unroll
        for (int kk = 0; kk < 16; ++kk) {
            const float4 a4 = *(const float4*)&As[kk][ty << 2];
            const float4 b4 = *(const float4*)&Bs[kk][tx << 2];
            const float aa[4] = {a4.x, a4.y, a4.z, a4.w};
            const float bb[4] = {b4.x, b4.y, b4.z, b4.w};
#pragma unroll
            for (int i = 0; i < 4; ++i)
#pragma unroll
                for (int j = 0; j < 4; ++j)
                    acc[i][j] = fmaf(aa[i], bb[j], acc[i][j]);
        }
    }
    __syncthreads();
#pragma unroll
    for (int i = 0; i < 4; ++i)
#pragma unroll
        for (int j = 0; j < 4; ++j)
            sC[((ty << 2) + i) * 69 + (tx << 2) + j] = acc[i][j];
    __syncthreads();
    for (int idx = tid; idx < 64 * DTRANK; idx += 256) {
        const int t = idx / DTRANK, r = idx - t * DTRANK;
        dt[(size_t)(m0 + t) * DTRANK + r] = sC[t * 69 + r];
    }
    for (int idx = tid; idx < 64 * 32; idx += 256) {
        const int t = idx >> 5, c = idx & 31;
        BCt[((size_t)(b * LBATCH + tl0 + t)) * 32 + c] = sC[t * 69 + DTRANK + c];
    }
}

// ---------------------------------------------------------------------------
// delta = softplus(dt @ dt_proj^T + dt_proj_b), written col-major [b][d][t]
// 768 blocks (full GPU), 256 threads.
// ---------------------------------------------------------------------------
__global__ __launch_bounds__(256) void delta_kernel(const float* __restrict__ dt,
                                                    const float* __restrict__ dtw,
                                                    const float* __restrict__ dtb,
                                                    float* __restrict__ delta_col)
{
    const int t0g = blockIdx.x * 64;
    const int d0 = blockIdx.y * 64;
    const int b = t0g >> 12, tl0 = t0g & 4095;
    __shared__ float sdt[64][13];
    const int tid = threadIdx.x;
    for (int idx = tid; idx < 64 * DTRANK; idx += 256)
        sdt[idx / DTRANK][idx % DTRANK] = dt[(size_t)t0g * DTRANK + idx];
    __syncthreads();
    const int tl = tid & 63;
    const int dl0 = tid >> 6;
#pragma unroll
    for (int j = 0; j < 16; ++j) {
        const int d = d0 + dl0 + 4 * j;
        float a = dtb[d];
#pragma unroll
        for (int r = 0; r < DTRANK; ++r)
            a = fmaf(sdt[tl][r], dtw[d * DTRANK + r], a);
        delta_col[((size_t)(b * DI + d)) * LBATCH + tl0 + tl] = softplus_f(a);
    }
}

// ---------------------------------------------------------------------------
// Selective scan v4: 512 threads/block, 128 segments x 32 steps, 4 states/thread.
// Thread (s = tid>>2 in 0..127, n4 = tid&3): segment s, states 4n4..4n4+3.
// Middle: 8 waves x 2 states; 64-lane scan per segment-half + affine stitch.
// ---------------------------------------------------------------------------
__global__ __launch_bounds__(512) void scan_kernel(const float* __restrict__ delta_col,
                                                   const float* __restrict__ u_col,
                                                   const float* __restrict__ BCt,
                                                   const float* __restrict__ z_col,
                                                   const float* __restrict__ A_log,
                                                   const float* __restrict__ Dv,
                                                   float* __restrict__ y_col)
{
    const int bd = blockIdx.x;       // b*384 + d
    const int b = bd / DI;
    const int d = bd - b * DI;
    const int tid = threadIdx.x;
    const int n4 = tid & 3;          // state quad (states 4n4..4n4+3)
    const int s = tid >> 2;          // segment 0..127

    const float4 al = *(const float4*)(A_log + d * DSTATE + 4 * n4);
    // An2[q] = -exp(A_log) * log2(e)  -> a = exp2(delta * An2)
    float An2[4];
    An2[0] = -__expf(al.x) * 1.44269504f;
    An2[1] = -__expf(al.y) * 1.44269504f;
    An2[2] = -__expf(al.z) * 1.44269504f;
    An2[3] = -__expf(al.w) * 1.44269504f;
    const float Dd = Dv[d];

    const int t0 = s * 32;
    const float* dp = delta_col + (size_t)bd * LBATCH + t0;
    const float* up = u_col + (size_t)bd * LBATCH + t0;
    const float* zp = z_col + (size_t)bd * LBATCH + t0;
    const float* bc = BCt + ((size_t)b * LBATCH + t0) * 32 + 4 * n4;
    float* yp = y_col + (size_t)bd * LBATCH + t0;

    __shared__ float aggA[128 * 20];
    __shared__ float aggB[128 * 20];
    __shared__ float hst[128 * 20];

    // ---- phase 1: segment affine aggregate for 4 states (32 steps) ----
    float Ag[4] = {1.f, 1.f, 1.f, 1.f}, Bg[4] = {0.f, 0.f, 0.f, 0.f};
    {
        const float* bci = bc;
        for (int i = 0; i < 32; i += 4) {
            const float4 d4 = *(const float4*)(dp + i);
            const float4 u4 = *(const float4*)(up + i);
            const float dls[4] = {d4.x, d4.y, d4.z, d4.w};
            const float uus[4] = {u4.x, u4.y, u4.z, u4.w};
#pragma unroll
            for (int j = 0; j < 4; ++j) {
                const float4 bm4 = *(const float4*)(bci + j * 32);
                const float du = dls[j] * uus[j];
                const float bms[4] = {bm4.x, bm4.y, bm4.z, bm4.w};
#pragma unroll
                for (int q = 0; q < 4; ++q) {
                    const float a = exp2f(dls[j] * An2[q]);
                    Bg[q] = fmaf(a, Bg[q], du * bms[q]);
                    Ag[q] *= a;
                }
            }
            bci += 128;
        }
    }
    *(float4*)&aggA[s * 20 + 4 * n4] = make_float4(Ag[0], Ag[1], Ag[2], Ag[3]);
    *(float4*)&aggB[s * 20 + 4 * n4] = make_float4(Bg[0], Bg[1], Bg[2], Bg[3]);
    __syncthreads();

    // ---- middle: per-state inclusive scan over 128 segment aggregates ----
    {
        const int w = tid >> 6;      // wave 0..7 -> states 2w, 2w+1
        const int lane = tid & 63;
#pragma unroll
        for (int r = 0; r < 2; ++r) {
            const int n = w * 2 + r;
            // first half: segments 0..63
            float sA = aggA[lane * 20 + n];
            float sB = aggB[lane * 20 + n];
#pragma unroll
            for (int o = 1; o < 64; o <<= 1) {
                const float pA = __shfl_up(sA, (unsigned)o, 64);
                const float pB = __shfl_up(sB, (unsigned)o, 64);
                if (lane >= o) { sB = fmaf(sA, pB, sB); sA *= pA; }
            }
            const float B0tot = __shfl(sB, 63, 64);
            const float ex0 = __shfl_up(sB, 1, 64);
            hst[lane * 20 + n] = (lane == 0) ? 0.f : ex0;
            // second half: segments 64..127, stitched with half-0 total
            float tA = aggA[(64 + lane) * 20 + n];
            float tB = aggB[(64 + lane) * 20 + n];
#pragma unroll
            for (int o = 1; o < 64; o <<= 1) {
                const float pA = __shfl_up(tA, (unsigned)o, 64);
                const float pB = __shfl_up(tB, (unsigned)o, 64);
                if (lane >= o) { tB = fmaf(tA, pB, tB); tA *= pA; }
            }
            const float exA = (lane == 0) ? 1.f : __shfl_up(tA, 1, 64);
            const float exB = (lane == 0) ? 0.f : __shfl_up(tB, 1, 64);
            hst[(64 + lane) * 20 + n] = fmaf(exA, B0tot, exB);
        }
    }
    __syncthreads();

    // ---- phase 2: replay with exact incoming state ----
    const float4 h4 = *(const float4*)&hst[s * 20 + 4 * n4];
    float h[4] = {h4.x, h4.y, h4.z, h4.w};
    {
        const float* bci = bc;
        for (int i = 0; i < 32; i += 4) {
            const float4 d4 = *(const float4*)(dp + i);
            const float4 u4 = *(const float4*)(up + i);
            const float4 z4 = *(const float4*)(zp + i);
            const float dls[4] = {d4.x, d4.y, d4.z, d4.w};
            const float uus[4] = {u4.x, u4.y, u4.z, u4.w};
            const float zzs[4] = {z4.x, z4.y, z4.z, z4.w};
#pragma unroll
            for (int j = 0; j < 4; ++j) {
                const float4 bm4 = *(const float4*)(bci + j * 32);
                const float4 cm4 = *(const float4*)(bci + j * 32 + 16);
                const float du = dls[j] * uus[j];
                const float bms[4] = {bm4.x, bm4.y, bm4.z, bm4.w};
                const float cms[4] = {cm4.x, cm4.y, cm4.z, cm4.w};
                float p = 0.f;
#pragma unroll
                for (int q = 0; q < 4; ++q) {
                    const float a = exp2f(dls[j] * An2[q]);
                    h[q] = fmaf(a, h[q], du * bms[q]);
                    p = fmaf(h[q], cms[q], p);
                }
                p = dpp_add<0xB1>(p);   // quad xor1
                p = dpp_add<0x4E>(p);   // quad xor2
                if (n4 == 0)
                    yp[i + j] = (p + uus[j] * Dd) * silu_f(zzs[j]);
            }
            bci += 128;
        }
    }
}

// ---------------------------------------------------------------------------
extern "C" void kernel_launch(void* const* d_in, const int* in_sizes, int n_in,
                              void* d_out, int out_size, void* d_ws, size_t ws_size,
                              hipStream_t stream)
{
    const float* x         = (const float*)d_in[0];
    const float* down_w    = (const float*)d_in[1];
    const float* up_w      = (const float*)d_in[2];
    const float* in_proj_w = (const float*)d_in[3];
    const float* conv_w    = (const float*)d_in[4];
    const float* conv_b    = (const float*)d_in[5];
    const float* x_proj_w  = (const float*)d_in[6];
    const float* dt_proj_w = (const float*)d_in[7];
    const float* dt_proj_b = (const float*)d_in[8];
    const float* A_log     = (const float*)d_in[9];
    const float* D_ssm     = (const float*)d_in[10];
    const float* out_proj_w= (const float*)d_in[11];
    const float* ln_g      = (const float*)d_in[12];
    const float* ln_b      = (const float*)d_in[13];
    float* out = (float*)d_out;
    float* ws = (float*)d_ws;

    // fp32 workspace
    float* xi_col    = ws;                        // 2*384*4096 = 3145728
    float* z_col     = xi_col + 3145728;          // 3145728
    float* u_col     = z_col + 3145728;           // 3145728
    float* y_col     = u_col + 3145728;           // 3145728
    float* BCt       = y_col + 3145728;           // 262144
    float* dt        = BCt + 262144;              // 98304
    float* delta_col = xi_col;                    // alias: xi dead after conv
    // bf16 workspace
    unsigned short* xdb    = (unsigned short*)(dt + 98304);   // 1572864
    unsigned short* gb     = xdb;                 // alias: xdb dead after gemm2
    unsigned short* wdownb = xdb + 1572864;       // 147456
    unsigned short* winb   = wdownb + 147456;     // 147456
    unsigned short* woutb  = winb + 147456;       // 73728
    unsigned short* wupb   = woutb + 73728;       // 147456

    // 0. all weight casts in one launch
    cast_w4<<<dim3(144, 4), 256, 0, stream>>>(down_w, in_proj_w, out_proj_w, up_w,
                                              wdownb, winb, woutb, wupb);
    // 1. xd = x @ down_w^T  (fp32 A converted in staging) -> xdb bf16 row-major
    gemm_mfma<0, true><<<dim3(3, 128), 256, 0, stream>>>(x, wdownb, xdb, nullptr, nullptr, DM, RR);
    // 2. xz = xd @ in_proj^T -> xi_col, z_col (fp32 col-major)
    gemm_mfma<1, false><<<dim3(12, 128), 256, 0, stream>>>(xdb, winb, xi_col, z_col, nullptr, RR, 2 * DI);
    // 3. depthwise conv4 + silu -> u_col
    conv_silu_kernel<<<768, 256, 0, stream>>>(xi_col, conv_w, conv_b, u_col);
    // 4. x_dbl = u @ x_proj^T -> dt, BCt
    gemm_xdbl<<<128, 256, 0, stream>>>(u_col, x_proj_w, dt, BCt);
    // 5. delta = softplus(dt @ dt_proj^T + b) -> delta_col (aliases xi_col)
    delta_kernel<<<dim3(128, 6), 256, 0, stream>>>(dt, dt_proj_w, dt_proj_b, delta_col);
    // 6. selective scan v4 + gating -> y_col
    scan_kernel<<<768, 512, 0, stream>>>(delta_col, u_col, BCt, z_col, A_log, D_ssm, y_col);
    // 7. m = y @ out_proj^T + LN + GELU (transpose fused in staging) -> gb
    gemm_ln_mfma<<<128, 256, 0, stream>>>(y_col, woutb, ln_g, ln_b, gb);
    // 8. out = x + g @ up_w^T (fp32 store)
    gemm_mfma<2, false><<<dim3(12, 128), 256, 0, stream>>>(gb, wupb, out, nullptr, x, RR, DM);
}

// Round 7
// 271.885 us; speedup vs baseline: 1.1357x; 1.0495x over previous
//
#include <hip/hip_runtime.h>
#include <math.h>

// Problem constants
#define LBATCH 4096  // tokens per mamba batch (b=2)
#define DM 768
#define RR 192
#define DI 384
#define DSTATE 16
#define DTRANK 12

typedef __attribute__((ext_vector_type(8))) short s16x8;   // 8 bf16 in 4 VGPRs
typedef __attribute__((ext_vector_type(4))) float f32x4;   // MFMA accumulator

__device__ __forceinline__ float silu_f(float x) { return x / (1.f + __expf(-x)); }
__device__ __forceinline__ float softplus_f(float x) { return x > 20.f ? x : log1pf(__expf(x)); }

__device__ __forceinline__ unsigned short f2bf(float f) {   // RNE fp32->bf16
    unsigned u = __float_as_uint(f);
    u += 0x7FFFu + ((u >> 16) & 1u);
    return (unsigned short)(u >> 16);
}

// load 8 consecutive fp32 and pack to 8 bf16 (4 VGPRs)
__device__ __forceinline__ s16x8 pack_bf8(const float* __restrict__ p) {
    const float4 f0 = *(const float4*)p;
    const float4 f1 = *(const float4*)(p + 4);
    union { s16x8 v; unsigned short u[8]; } pk;
    pk.u[0] = f2bf(f0.x); pk.u[1] = f2bf(f0.y); pk.u[2] = f2bf(f0.z); pk.u[3] = f2bf(f0.w);
    pk.u[4] = f2bf(f1.x); pk.u[5] = f2bf(f1.y); pk.u[6] = f2bf(f1.z); pk.u[7] = f2bf(f1.w);
    return pk.v;
}

// DPP partial sums across aligned lane groups (VALU pipe, no LDS).
template <int CTRL>
__device__ __forceinline__ float dpp_add(float x) {
    const int y = __builtin_amdgcn_update_dpp(0, __float_as_int(x), CTRL, 0xF, 0xF, false);
    return x + __int_as_float(y);
}

// ---------------------------------------------------------------------------
// bf16 MFMA GEMM: C(M,N) = A(M,K) @ W(N,K)^T, 64x64 tile, 4 waves (wave: 64Mx16N)
// CVTA: A is fp32, converted to bf16 during LDS staging.
// CVTW: W is fp32, converted to bf16 during LDS staging (no separate cast pass).
// MODE 0: store C as bf16 row-major
// MODE 1: transposed split store -> fp32 xi_col[b][ch][t] / z_col[b][ch][t]
// MODE 2: store fp32 C = acc + X (residual), row-major
// ---------------------------------------------------------------------------
template <int MODE, bool CVTA, bool CVTW>
__global__ __launch_bounds__(256) void gemm_mfma(const void* __restrict__ Araw,
                                                 const void* __restrict__ Wraw,
                                                 void* __restrict__ C0,
                                                 void* __restrict__ C1,
                                                 const float* __restrict__ X,
                                                 int K, int N)
{
    __shared__ unsigned short As[64 * 40];
    __shared__ unsigned short Ws[64 * 40];
    __shared__ float sC[(MODE == 1) ? 64 * 65 : 1];

    const int tid = threadIdx.x;
    const int wave = tid >> 6, lane = tid & 63;
    const int quad = lane >> 4, l16 = lane & 15;
    const int m0 = blockIdx.y * 64, n0 = blockIdx.x * 64;

    f32x4 acc[4] = {};

    const int sr = tid >> 2;          // staging row 0..63
    const int sc = (tid & 3) * 8;     // staging k-offset

    for (int k0 = 0; k0 < K; k0 += 32) {
        s16x8 av, wv;
        if (CVTA) {
            av = pack_bf8((const float*)Araw + (size_t)(m0 + sr) * K + k0 + sc);
        } else {
            av = *(const s16x8*)((const unsigned short*)Araw + (size_t)(m0 + sr) * K + k0 + sc);
        }
        if (CVTW) {
            wv = pack_bf8((const float*)Wraw + (size_t)(n0 + sr) * K + k0 + sc);
        } else {
            wv = *(const s16x8*)((const unsigned short*)Wraw + (size_t)(n0 + sr) * K + k0 + sc);
        }
        __syncthreads();
        *(s16x8*)&As[sr * 40 + sc] = av;
        *(s16x8*)&Ws[sr * 40 + sc] = wv;
        __syncthreads();
        const s16x8 b = *(const s16x8*)&Ws[(wave * 16 + l16) * 40 + quad * 8];
#pragma unroll
        for (int mi = 0; mi < 4; ++mi) {
            const s16x8 a = *(const s16x8*)&As[(mi * 16 + l16) * 40 + quad * 8];
            acc[mi] = __builtin_amdgcn_mfma_f32_16x16x32_bf16(a, b, acc[mi], 0, 0, 0);
        }
    }

    if (MODE == 0) {
        unsigned short* Crow = (unsigned short*)C0;
#pragma unroll
        for (int mi = 0; mi < 4; ++mi)
#pragma unroll
            for (int r = 0; r < 4; ++r)
                Crow[(size_t)(m0 + mi * 16 + quad * 4 + r) * N + n0 + wave * 16 + l16] =
                    f2bf(acc[mi][r]);
    } else if (MODE == 2) {
        float* Co = (float*)C0;
#pragma unroll
        for (int mi = 0; mi < 4; ++mi)
#pragma unroll
            for (int r = 0; r < 4; ++r) {
                const size_t off =
                    (size_t)(m0 + mi * 16 + quad * 4 + r) * N + n0 + wave * 16 + l16;
                Co[off] = acc[mi][r] + X[off];
            }
    } else {
#pragma unroll
        for (int mi = 0; mi < 4; ++mi)
#pragma unroll
            for (int r = 0; r < 4; ++r)
                sC[(wave * 16 + l16) * 65 + mi * 16 + quad * 4 + r] = acc[mi][r];
        __syncthreads();
        const int b = m0 >> 12, tl0 = m0 & 4095;
        for (int idx = tid; idx < 1024; idx += 256) {
            const int nn = idx >> 4, t4 = (idx & 15) << 2;
            const float4 v = make_float4(sC[nn * 65 + t4], sC[nn * 65 + t4 + 1],
                                         sC[nn * 65 + t4 + 2], sC[nn * 65 + t4 + 3]);
            const int gch = n0 + nn;
            float* dst = (gch < DI)
                             ? (float*)C0 + ((size_t)(b * DI + gch)) * LBATCH
                             : (float*)C1 + ((size_t)(b * DI + gch - DI)) * LBATCH;
            *(float4*)(dst + tl0 + t4) = v;
        }
    }
}

// ---------------------------------------------------------------------------
// m = y @ out_proj^T (bf16 MFMA, K=384, N=192) + LayerNorm + exact GELU -> bf16 G.
// A is fp32 y_col [b][d][t]: transposed + cast during LDS staging (fused).
// W is fp32 out_proj, converted during staging. Tile 64M x 192N; wave-local LN.
// ---------------------------------------------------------------------------
__global__ __launch_bounds__(256) void gemm_ln_mfma(const float* __restrict__ ycol,
                                                    const float* __restrict__ Wf,
                                                    const float* __restrict__ lng,
                                                    const float* __restrict__ lnb,
                                                    unsigned short* __restrict__ G)
{
    __shared__ unsigned short As[64 * 40];
    __shared__ unsigned short Ws[192 * 40];
    const int tid = threadIdx.x;
    const int wave = tid >> 6, lane = tid & 63;
    const int quad = lane >> 4, l16 = lane & 15;
    const int m0 = blockIdx.x * 64;
    const int b = m0 >> 12, tl0 = m0 & 4095;

    f32x4 acc[12] = {};
    const int sr = tid >> 2, sc = (tid & 3) * 8;
    // A-staging map: d-pair kd2 = tid>>4 (0..15), token offset tt0 = (tid&15)*4
    const int kd2 = tid >> 4, tt0 = (tid & 15) << 2;

    for (int k0 = 0; k0 < DI; k0 += 32) {
        const float* y0 = ycol + ((size_t)(b * DI + k0 + 2 * kd2)) * LBATCH + tl0 + tt0;
        const float4 v0 = *(const float4*)y0;            // d = k0+2*kd2,   t = tt0..tt0+3
        const float4 v1 = *(const float4*)(y0 + LBATCH); // d = k0+2*kd2+1
        const float* wp = Wf + (size_t)sr * DI + k0 + sc;
        const s16x8 w0 = pack_bf8(wp);
        const s16x8 w1 = pack_bf8(wp + (size_t)64 * DI);
        const s16x8 w2 = pack_bf8(wp + (size_t)128 * DI);
        __syncthreads();
        {
            const float e0[4] = {v0.x, v0.y, v0.z, v0.w};
            const float e1[4] = {v1.x, v1.y, v1.z, v1.w};
#pragma unroll
            for (int r = 0; r < 4; ++r) {
                const unsigned pair =
                    (unsigned)f2bf(e0[r]) | ((unsigned)f2bf(e1[r]) << 16);
                *(unsigned*)&As[(tt0 + r) * 40 + 2 * kd2] = pair;
            }
        }
        *(s16x8*)&Ws[sr * 40 + sc] = w0;
        *(s16x8*)&Ws[(sr + 64) * 40 + sc] = w1;
        *(s16x8*)&Ws[(sr + 128) * 40 + sc] = w2;
        __syncthreads();
        const s16x8 a = *(const s16x8*)&As[(wave * 16 + l16) * 40 + quad * 8];
#pragma unroll
        for (int j = 0; j < 12; ++j) {
            const s16x8 bb = *(const s16x8*)&Ws[(j * 16 + l16) * 40 + quad * 8];
            acc[j] = __builtin_amdgcn_mfma_f32_16x16x32_bf16(a, bb, acc[j], 0, 0, 0);
        }
    }

    // LayerNorm stats per row (row = m0 + wave*16 + quad*4 + r), wave-local via DPP
    float s[4] = {0, 0, 0, 0}, q[4] = {0, 0, 0, 0};
#pragma unroll
    for (int j = 0; j < 12; ++j)
#pragma unroll
        for (int r = 0; r < 4; ++r) {
            s[r] += acc[j][r];
            q[r] = fmaf(acc[j][r], acc[j][r], q[r]);
        }
#pragma unroll
    for (int r = 0; r < 4; ++r) {
        s[r] = dpp_add<0xB1>(s[r]); s[r] = dpp_add<0x4E>(s[r]);
        s[r] = dpp_add<0x124>(s[r]); s[r] = dpp_add<0x128>(s[r]);
        q[r] = dpp_add<0xB1>(q[r]); q[r] = dpp_add<0x4E>(q[r]);
        q[r] = dpp_add<0x124>(q[r]); q[r] = dpp_add<0x128>(q[r]);
    }
    float mu[4], rs[4];
#pragma unroll
    for (int r = 0; r < 4; ++r) {
        mu[r] = s[r] * (1.f / 192.f);
        const float var = q[r] * (1.f / 192.f) - mu[r] * mu[r];
        rs[r] = rsqrtf(var + 1e-5f);
    }
    float gv[12], bv[12];
#pragma unroll
    for (int j = 0; j < 12; ++j) { gv[j] = lng[j * 16 + l16]; bv[j] = lnb[j * 16 + l16]; }
#pragma unroll
    for (int j = 0; j < 12; ++j)
#pragma unroll
        for (int r = 0; r < 4; ++r) {
            const float v = (acc[j][r] - mu[r]) * rs[r] * gv[j] + bv[j];
            const float ge = 0.5f * v * (1.f + erff(v * 0.70710678118654752f));
            G[(size_t)(m0 + wave * 16 + quad * 4 + r) * RR + j * 16 + l16] = f2bf(ge);
        }
}

// ---------------------------------------------------------------------------
// Depthwise causal conv (width 4) + SiLU.  One block per (b, channel) row.
// ---------------------------------------------------------------------------
__global__ __launch_bounds__(256) void conv_silu_kernel(const float* __restrict__ xi_col,
                                                        const float* __restrict__ cw,
                                                        const float* __restrict__ cb,
                                                        float* __restrict__ u_col)
{
    const int row = blockIdx.x;      // b*384 + c
    const int c = row % DI;
    const float* xp = xi_col + (size_t)row * LBATCH;
    float* up = u_col + (size_t)row * LBATCH;
    const float w0 = cw[c * 4 + 0], w1 = cw[c * 4 + 1], w2 = cw[c * 4 + 2], w3 = cw[c * 4 + 3];
    const float bb = cb[c];
    for (int t = threadIdx.x; t < LBATCH; t += 256) {
        const float x3 = xp[t];
        const float x2 = (t >= 1) ? xp[t - 1] : 0.f;
        const float x1 = (t >= 2) ? xp[t - 2] : 0.f;
        const float x0 = (t >= 3) ? xp[t - 3] : 0.f;
        const float v = bb + w0 * x0 + w1 * x1 + w2 * x2 + w3 * x3;
        up[t] = silu_f(v);
    }
}

// ---------------------------------------------------------------------------
// x_dbl = u @ x_proj^T (N=44, K=384), A read col-major (u_col). 32-row tiles
// -> 256 blocks (full GPU). Outputs: dt row-major, BCt interleaved [b][t][32].
// ---------------------------------------------------------------------------
__global__ __launch_bounds__(256) void gemm_xdbl(const float* __restrict__ u_col,
                                                 const float* __restrict__ Wx,
                                                 float* __restrict__ dt,
                                                 float* __restrict__ BCt)
{
    __shared__ float As[16][33];
    __shared__ float Bs[16][68];
    __shared__ float sC[32 * 69];
    const int tid = threadIdx.x;
    const int ty = tid >> 4, tx = tid & 15;
    const int m0 = blockIdx.x * 32;
    const int b = m0 >> 12, tl0 = m0 & 4095;

    float acc[2][4] = {};

    for (int k0 = 0; k0 < DI; k0 += 16) {
        __syncthreads();
        {
            const int m = tid & 31;
            const int kk0 = tid >> 5;  // 0..7
            As[kk0][m] = u_col[((size_t)(b * DI + k0 + kk0)) * LBATCH + tl0 + m];
            As[kk0 + 8][m] = u_col[((size_t)(b * DI + k0 + kk0 + 8)) * LBATCH + tl0 + m];
        }
        if (tid < 176) {
            const int n = tid >> 2;
            const int lk2 = (tid & 3) << 2;
            const float4 wv = *(const float4*)(Wx + (size_t)n * DI + k0 + lk2);
            Bs[lk2 + 0][n] = wv.x; Bs[lk2 + 1][n] = wv.y; Bs[lk2 + 2][n] = wv.z; Bs[lk2 + 3][n] = wv.w;
        }
        __syncthreads();
#pragma unroll
        for (int kk = 0; kk < 16; ++kk) {
            const float a0 = As[kk][ty * 2 + 0];
            const float a1 = As[kk][ty * 2 + 1];
            const float4 b4 = *(const float4*)&Bs[kk][tx << 2];
            const float bb[4] = {b4.x, b4.y, b4.z, b4.w};
#pragma unroll
            for (int j = 0; j < 4; ++j) {
                acc[0][j] = fmaf(a0, bb[j], acc[0][j]);
                acc[1][j] = fmaf(a1, bb[j], acc[1][j]);
            }
        }
    }
    __syncthreads();
#pragma unroll
    for (int i = 0; i < 2; ++i)
#pragma unroll
        for (int j = 0; j < 4; ++j)
            sC[(ty * 2 + i) * 69 + (tx << 2) + j] = acc[i][j];
    __syncthreads();
    for (int idx = tid; idx < 32 * DTRANK; idx += 256) {
        const int t = idx / DTRANK, r = idx - t * DTRANK;
        dt[(size_t)(m0 + t) * DTRANK + r] = sC[t * 69 + r];
    }
    for (int idx = tid; idx < 32 * 32; idx += 256) {
        const int t = idx >> 5, c = idx & 31;
        BCt[((size_t)(b * LBATCH + tl0 + t)) * 32 + c] = sC[t * 69 + DTRANK + c];
    }
}

// ---------------------------------------------------------------------------
// delta = softplus(dt @ dt_proj^T + dt_proj_b), written col-major [b][d][t]
// ---------------------------------------------------------------------------
__global__ __launch_bounds__(256) void delta_kernel(const float* __restrict__ dt,
                                                    const float* __restrict__ dtw,
                                                    const float* __restrict__ dtb,
                                                    float* __restrict__ delta_col)
{
    const int t0g = blockIdx.x * 64;
    const int d0 = blockIdx.y * 64;
    const int b = t0g >> 12, tl0 = t0g & 4095;
    __shared__ float sdt[64][13];
    const int tid = threadIdx.x;
    for (int idx = tid; idx < 64 * DTRANK; idx += 256)
        sdt[idx / DTRANK][idx % DTRANK] = dt[(size_t)t0g * DTRANK + idx];
    __syncthreads();
    const int tl = tid & 63;
    const int dl0 = tid >> 6;
#pragma unroll
    for (int j = 0; j < 16; ++j) {
        const int d = d0 + dl0 + 4 * j;
        float a = dtb[d];
#pragma unroll
        for (int r = 0; r < DTRANK; ++r)
            a = fmaf(sdt[tl][r], dtw[d * DTRANK + r], a);
        delta_col[((size_t)(b * DI + d)) * LBATCH + tl0 + tl] = softplus_f(a);
    }
}

// ---------------------------------------------------------------------------
// Selective scan v5: 512 threads, 128 segments x 32 steps, 4 states/thread.
// Stride-21 agg arrays (odd -> conflict-free middle scan); y staged in LDS
// ybuf (stride 36, aliases dead aggA/aggB) and flushed as coalesced float4.
// ---------------------------------------------------------------------------
__global__ __launch_bounds__(512) void scan_kernel(const float* __restrict__ delta_col,
                                                   const float* __restrict__ u_col,
                                                   const float* __restrict__ BCt,
                                                   const float* __restrict__ z_col,
                                                   const float* __restrict__ A_log,
                                                   const float* __restrict__ Dv,
                                                   float* __restrict__ y_col)
{
    const int bd = blockIdx.x;       // b*384 + d
    const int b = bd / DI;
    const int d = bd - b * DI;
    const int tid = threadIdx.x;
    const int n4 = tid & 3;          // state quad (states 4n4..4n4+3)
    const int s = tid >> 2;          // segment 0..127

    __shared__ float smem[128 * 21 * 3];          // 32.25 KB
    float* aggA = smem;                            // [128*21]
    float* aggB = smem + 128 * 21;                 // [128*21]
    float* hst  = smem + 128 * 21 * 2;             // [128*21]
    float* ybuf = smem;                            // aliases aggA/aggB (dead after middle)

    const float4 al = *(const float4*)(A_log + d * DSTATE + 4 * n4);
    float An2[4];
    An2[0] = -__expf(al.x) * 1.44269504f;
    An2[1] = -__expf(al.y) * 1.44269504f;
    An2[2] = -__expf(al.z) * 1.44269504f;
    An2[3] = -__expf(al.w) * 1.44269504f;
    const float Dd = Dv[d];

    const int t0 = s * 32;
    const float* dp = delta_col + (size_t)bd * LBATCH + t0;
    const float* up = u_col + (size_t)bd * LBATCH + t0;
    const float* zp = z_col + (size_t)bd * LBATCH + t0;
    const float* bc = BCt + ((size_t)b * LBATCH + t0) * 32 + 4 * n4;

    // ---- phase 1: segment affine aggregate for 4 states (32 steps) ----
    float Ag[4] = {1.f, 1.f, 1.f, 1.f}, Bg[4] = {0.f, 0.f, 0.f, 0.f};
    {
        const float* bci = bc;
        for (int i = 0; i < 32; i += 4) {
            const float4 d4 = *(const float4*)(dp + i);
            const float4 u4 = *(const float4*)(up + i);
            const float dls[4] = {d4.x, d4.y, d4.z, d4.w};
            const float uus[4] = {u4.x, u4.y, u4.z, u4.w};
#pragma unroll
            for (int j = 0; j < 4; ++j) {
                const float4 bm4 = *(const float4*)(bci + j * 32);
                const float du = dls[j] * uus[j];
                const float bms[4] = {bm4.x, bm4.y, bm4.z, bm4.w};
#pragma unroll
                for (int q = 0; q < 4; ++q) {
                    const float a = exp2f(dls[j] * An2[q]);
                    Bg[q] = fmaf(a, Bg[q], du * bms[q]);
                    Ag[q] *= a;
                }
            }
            bci += 128;
        }
    }
#pragma unroll
    for (int q = 0; q < 4; ++q) {
        aggA[s * 21 + 4 * n4 + q] = Ag[q];
        aggB[s * 21 + 4 * n4 + q] = Bg[q];
    }
    __syncthreads();

    // ---- middle: per-state inclusive scan over 128 segment aggregates ----
    {
        const int w = tid >> 6;      // wave 0..7 -> states 2w, 2w+1
        const int lane = tid & 63;
#pragma unroll
        for (int r = 0; r < 2; ++r) {
            const int n = w * 2 + r;
            // first half: segments 0..63
            float sA = aggA[lane * 21 + n];
            float sB = aggB[lane * 21 + n];
#pragma unroll
            for (int o = 1; o < 64; o <<= 1) {
                const float pA = __shfl_up(sA, (unsigned)o, 64);
                const float pB = __shfl_up(sB, (unsigned)o, 64);
                if (lane >= o) { sB = fmaf(sA, pB, sB); sA *= pA; }
            }
            const float B0tot = __shfl(sB, 63, 64);
            const float ex0 = __shfl_up(sB, 1, 64);
            hst[lane * 21 + n] = (lane == 0) ? 0.f : ex0;
            // second half: segments 64..127, stitched with half-0 total
            float tA = aggA[(64 + lane) * 21 + n];
            float tB = aggB[(64 + lane) * 21 + n];
#pragma unroll
            for (int o = 1; o < 64; o <<= 1) {
                const float pA = __shfl_up(tA, (unsigned)o, 64);
                const float pB = __shfl_up(tB, (unsigned)o, 64);
                if (lane >= o) { tB = fmaf(tA, pB, tB); tA *= pA; }
            }
            const float exA = (lane == 0) ? 1.f : __shfl_up(tA, 1, 64);
            const float exB = (lane == 0) ? 0.f : __shfl_up(tB, 1, 64);
            hst[(64 + lane) * 21 + n] = fmaf(exA, B0tot, exB);
        }
    }
    __syncthreads();

    // ---- phase 2: replay with exact incoming state; y -> LDS ybuf ----
    float h[4];
#pragma unroll
    for (int q = 0; q < 4; ++q) h[q] = hst[s * 21 + 4 * n4 + q];
    {
        const float* bci = bc;
        for (int i = 0; i < 32; i += 4) {
            const float4 d4 = *(const float4*)(dp + i);
            const float4 u4 = *(const float4*)(up + i);
            const float4 z4 = *(const float4*)(zp + i);
            const float dls[4] = {d4.x, d4.y, d4.z, d4.w};
            const float uus[4] = {u4.x, u4.y, u4.z, u4.w};
            const float zzs[4] = {z4.x, z4.y, z4.z, z4.w};
#pragma unroll
            for (int j = 0; j < 4; ++j) {
                const float4 bm4 = *(const float4*)(bci + j * 32);
                const float4 cm4 = *(const float4*)(bci + j * 32 + 16);
                const float du = dls[j] * uus[j];
                const float bms[4] = {bm4.x, bm4.y, bm4.z, bm4.w};
                const float cms[4] = {cm4.x, cm4.y, cm4.z, cm4.w};
                float p = 0.f;
#pragma unroll
                for (int q = 0; q < 4; ++q) {
                    const float a = exp2f(dls[j] * An2[q]);
                    h[q] = fmaf(a, h[q], du * bms[q]);
                    p = fmaf(h[q], cms[q], p);
                }
                p = dpp_add<0xB1>(p);   // quad xor1
                p = dpp_add<0x4E>(p);   // quad xor2
                if (n4 == 0)
                    ybuf[s * 36 + i + j] = (p + uus[j] * Dd) * silu_f(zzs[j]);
            }
            bci += 128;
        }
    }
    __syncthreads();

    // ---- coalesced flush: LDS ybuf -> y_col row ----
    {
        float* yrow = y_col + (size_t)bd * LBATCH;
        for (int idx = tid; idx < 1024; idx += 512) {
            const int ss = idx >> 3, wg = (idx & 7) << 2;
            const float4 v = *(const float4*)&ybuf[ss * 36 + wg];
            *(float4*)(yrow + ss * 32 + wg) = v;
        }
    }
}

// ---------------------------------------------------------------------------
extern "C" void kernel_launch(void* const* d_in, const int* in_sizes, int n_in,
                              void* d_out, int out_size, void* d_ws, size_t ws_size,
                              hipStream_t stream)
{
    const float* x         = (const float*)d_in[0];
    const float* down_w    = (const float*)d_in[1];
    const float* up_w      = (const float*)d_in[2];
    const float* in_proj_w = (const float*)d_in[3];
    const float* conv_w    = (const float*)d_in[4];
    const float* conv_b    = (const float*)d_in[5];
    const float* x_proj_w  = (const float*)d_in[6];
    const float* dt_proj_w = (const float*)d_in[7];
    const float* dt_proj_b = (const float*)d_in[8];
    const float* A_log     = (const float*)d_in[9];
    const float* D_ssm     = (const float*)d_in[10];
    const float* out_proj_w= (const float*)d_in[11];
    const float* ln_g      = (const float*)d_in[12];
    const float* ln_b      = (const float*)d_in[13];
    float* out = (float*)d_out;
    float* ws = (float*)d_ws;

    // fp32 workspace
    float* xi_col    = ws;                        // 2*384*4096 = 3145728
    float* z_col     = xi_col + 3145728;          // 3145728
    float* u_col     = z_col + 3145728;           // 3145728
    float* y_col     = u_col + 3145728;           // 3145728
    float* BCt       = y_col + 3145728;           // 262144
    float* dt        = BCt + 262144;              // 98304
    float* delta_col = xi_col;                    // alias: xi dead after conv
    // bf16 workspace
    unsigned short* xdb = (unsigned short*)(dt + 98304);   // 1572864
    unsigned short* gb  = xdb;                    // alias: xdb dead after gemm2

    // 1. xd = x @ down_w^T  (both operands fp32, converted in staging) -> xdb bf16
    gemm_mfma<0, true, true><<<dim3(3, 128), 256, 0, stream>>>(x, down_w, xdb, nullptr, nullptr, DM, RR);
    // 2. xz = xd @ in_proj^T -> xi_col, z_col (fp32 col-major); W cvt in staging
    gemm_mfma<1, false, true><<<dim3(12, 128), 256, 0, stream>>>(xdb, in_proj_w, xi_col, z_col, nullptr, RR, 2 * DI);
    // 3. depthwise conv4 + silu -> u_col
    conv_silu_kernel<<<768, 256, 0, stream>>>(xi_col, conv_w, conv_b, u_col);
    // 4. x_dbl = u @ x_proj^T -> dt, BCt  (32-row tiles, 256 blocks)
    gemm_xdbl<<<256, 256, 0, stream>>>(u_col, x_proj_w, dt, BCt);
    // 5. delta = softplus(dt @ dt_proj^T + b) -> delta_col (aliases xi_col)
    delta_kernel<<<dim3(128, 6), 256, 0, stream>>>(dt, dt_proj_w, dt_proj_b, delta_col);
    // 6. selective scan v5 + gating -> y_col
    scan_kernel<<<768, 512, 0, stream>>>(delta_col, u_col, BCt, z_col, A_log, D_ssm, y_col);
    // 7. m = y @ out_proj^T + LN + GELU (transpose + W cvt fused in staging) -> gb
    gemm_ln_mfma<<<128, 256, 0, stream>>>(y_col, out_proj_w, ln_g, ln_b, gb);
    // 8. out = x + g @ up_w^T (fp32 store); W cvt in staging
    gemm_mfma<2, false, true><<<dim3(12, 128), 256, 0, stream>>>(gb, up_w, out, nullptr, x, RR, DM);
}

// Round 8
// 264.724 us; speedup vs baseline: 1.1664x; 1.0271x over previous
//
#include <hip/hip_runtime.h>
#include <math.h>

// Problem constants
#define LBATCH 4096  // tokens per mamba batch (b=2)
#define DM 768
#define RR 192
#define DI 384
#define DSTATE 16
#define DTRANK 12

typedef __attribute__((ext_vector_type(8))) short s16x8;   // 8 bf16 in 4 VGPRs
typedef __attribute__((ext_vector_type(4))) float f32x4;   // MFMA accumulator

#define EXP2F(x) __builtin_amdgcn_exp2f(x)
#define LOG2F(x) __builtin_amdgcn_logf(x)
#define RCPF(x)  __builtin_amdgcn_rcpf(x)
#define LOG2E 1.44269504f

__device__ __forceinline__ float silu_f(float x) {
    return x * RCPF(1.f + EXP2F(-LOG2E * x));
}
__device__ __forceinline__ float softplus_f(float x) {
    return 0.69314718056f * LOG2F(1.f + EXP2F(LOG2E * x));
}

__device__ __forceinline__ unsigned short f2bf(float f) {   // RNE fp32->bf16
    unsigned u = __float_as_uint(f);
    u += 0x7FFFu + ((u >> 16) & 1u);
    return (unsigned short)(u >> 16);
}

// load 8 consecutive fp32 and pack to 8 bf16 (4 VGPRs)
__device__ __forceinline__ s16x8 pack_bf8(const float* __restrict__ p) {
    const float4 f0 = *(const float4*)p;
    const float4 f1 = *(const float4*)(p + 4);
    union { s16x8 v; unsigned short u[8]; } pk;
    pk.u[0] = f2bf(f0.x); pk.u[1] = f2bf(f0.y); pk.u[2] = f2bf(f0.z); pk.u[3] = f2bf(f0.w);
    pk.u[4] = f2bf(f1.x); pk.u[5] = f2bf(f1.y); pk.u[6] = f2bf(f1.z); pk.u[7] = f2bf(f1.w);
    return pk.v;
}

// DPP partial sums across aligned lane groups (VALU pipe, no LDS).
template <int CTRL>
__device__ __forceinline__ float dpp_add(float x) {
    const int y = __builtin_amdgcn_update_dpp(0, __float_as_int(x), CTRL, 0xF, 0xF, false);
    return x + __int_as_float(y);
}

// ---------------------------------------------------------------------------
// bf16 MFMA GEMM: C(M,N) = A(M,K) @ W(N,K)^T, 64x64 tile, 4 waves (wave: 64Mx16N)
// CVTA: A is fp32, converted to bf16 during LDS staging.
// CVTW: W is fp32, converted to bf16 during LDS staging (no separate cast pass).
// MODE 0: store C as bf16 row-major
// MODE 1: transposed split store -> fp32 xi_col[b][ch][t] / z_col[b][ch][t]
// MODE 2: store fp32 C = acc + X (residual), row-major
// ---------------------------------------------------------------------------
template <int MODE, bool CVTA, bool CVTW>
__global__ __launch_bounds__(256) void gemm_mfma(const void* __restrict__ Araw,
                                                 const void* __restrict__ Wraw,
                                                 void* __restrict__ C0,
                                                 void* __restrict__ C1,
                                                 const float* __restrict__ X,
                                                 int K, int N)
{
    __shared__ unsigned short As[64 * 40];
    __shared__ unsigned short Ws[64 * 40];
    __shared__ float sC[(MODE == 1) ? 64 * 65 : 1];

    const int tid = threadIdx.x;
    const int wave = tid >> 6, lane = tid & 63;
    const int quad = lane >> 4, l16 = lane & 15;
    const int m0 = blockIdx.y * 64, n0 = blockIdx.x * 64;

    f32x4 acc[4] = {};

    const int sr = tid >> 2;          // staging row 0..63
    const int sc = (tid & 3) * 8;     // staging k-offset

    for (int k0 = 0; k0 < K; k0 += 32) {
        s16x8 av, wv;
        if (CVTA) {
            av = pack_bf8((const float*)Araw + (size_t)(m0 + sr) * K + k0 + sc);
        } else {
            av = *(const s16x8*)((const unsigned short*)Araw + (size_t)(m0 + sr) * K + k0 + sc);
        }
        if (CVTW) {
            wv = pack_bf8((const float*)Wraw + (size_t)(n0 + sr) * K + k0 + sc);
        } else {
            wv = *(const s16x8*)((const unsigned short*)Wraw + (size_t)(n0 + sr) * K + k0 + sc);
        }
        __syncthreads();
        *(s16x8*)&As[sr * 40 + sc] = av;
        *(s16x8*)&Ws[sr * 40 + sc] = wv;
        __syncthreads();
        const s16x8 b = *(const s16x8*)&Ws[(wave * 16 + l16) * 40 + quad * 8];
#pragma unroll
        for (int mi = 0; mi < 4; ++mi) {
            const s16x8 a = *(const s16x8*)&As[(mi * 16 + l16) * 40 + quad * 8];
            acc[mi] = __builtin_amdgcn_mfma_f32_16x16x32_bf16(a, b, acc[mi], 0, 0, 0);
        }
    }

    if (MODE == 0) {
        unsigned short* Crow = (unsigned short*)C0;
#pragma unroll
        for (int mi = 0; mi < 4; ++mi)
#pragma unroll
            for (int r = 0; r < 4; ++r)
                Crow[(size_t)(m0 + mi * 16 + quad * 4 + r) * N + n0 + wave * 16 + l16] =
                    f2bf(acc[mi][r]);
    } else if (MODE == 2) {
        float* Co = (float*)C0;
#pragma unroll
        for (int mi = 0; mi < 4; ++mi)
#pragma unroll
            for (int r = 0; r < 4; ++r) {
                const size_t off =
                    (size_t)(m0 + mi * 16 + quad * 4 + r) * N + n0 + wave * 16 + l16;
                Co[off] = acc[mi][r] + X[off];
            }
    } else {
#pragma unroll
        for (int mi = 0; mi < 4; ++mi)
#pragma unroll
            for (int r = 0; r < 4; ++r)
                sC[(wave * 16 + l16) * 65 + mi * 16 + quad * 4 + r] = acc[mi][r];
        __syncthreads();
        const int b = m0 >> 12, tl0 = m0 & 4095;
        for (int idx = tid; idx < 1024; idx += 256) {
            const int nn = idx >> 4, t4 = (idx & 15) << 2;
            const float4 v = make_float4(sC[nn * 65 + t4], sC[nn * 65 + t4 + 1],
                                         sC[nn * 65 + t4 + 2], sC[nn * 65 + t4 + 3]);
            const int gch = n0 + nn;
            float* dst = (gch < DI)
                             ? (float*)C0 + ((size_t)(b * DI + gch)) * LBATCH
                             : (float*)C1 + ((size_t)(b * DI + gch - DI)) * LBATCH;
            *(float4*)(dst + tl0 + t4) = v;
        }
    }
}

// ---------------------------------------------------------------------------
// m = y @ out_proj^T (bf16 MFMA, K=384, N=192) + LayerNorm + exact GELU -> bf16 G.
// v2: 32-row tiles -> 256 blocks (full chip). 4 waves: rowhalf = wave>>1
// (rows 0-15 / 16-31), nhalf = wave&1 (cols 0-95 / 96-191, 6 MFMA accs).
// LN stats: wave-local DPP partials combined across nhalf via small LDS.
// A is fp32 y_col [b][d][t]: transposed + cast during staging; W fp32 cvt.
// ---------------------------------------------------------------------------
__global__ __launch_bounds__(256) void gemm_ln_mfma(const float* __restrict__ ycol,
                                                    const float* __restrict__ Wf,
                                                    const float* __restrict__ lng,
                                                    const float* __restrict__ lnb,
                                                    unsigned short* __restrict__ G)
{
    __shared__ unsigned short As[32 * 40];
    __shared__ unsigned short Ws[192 * 40];
    __shared__ float psum[32][2][2];   // [row][nhalf][s|q]
    const int tid = threadIdx.x;
    const int wave = tid >> 6, lane = tid & 63;
    const int quad = lane >> 4, l16 = lane & 15;
    const int rowhalf = wave >> 1, nhalf = wave & 1;
    const int m0 = blockIdx.x * 32;
    const int b = m0 >> 12, tl0 = m0 & 4095;

    f32x4 acc[6] = {};
    const int sr = tid >> 2, sc = (tid & 3) * 8;   // W staging
    const int kd = tid >> 4, tt0 = (tid & 15) * 2; // A staging: d-pair 2kd, tokens tt0..tt0+1

    for (int k0 = 0; k0 < DI; k0 += 32) {
        const float* y0 = ycol + ((size_t)(b * DI + k0 + 2 * kd)) * LBATCH + tl0 + tt0;
        const float2 v0 = *(const float2*)y0;            // d = k0+2kd
        const float2 v1 = *(const float2*)(y0 + LBATCH); // d = k0+2kd+1
        const float* wp = Wf + (size_t)sr * DI + k0 + sc;
        const s16x8 w0 = pack_bf8(wp);
        const s16x8 w1 = pack_bf8(wp + (size_t)64 * DI);
        const s16x8 w2 = pack_bf8(wp + (size_t)128 * DI);
        __syncthreads();
        {
            const unsigned p0 = (unsigned)f2bf(v0.x) | ((unsigned)f2bf(v1.x) << 16);
            const unsigned p1 = (unsigned)f2bf(v0.y) | ((unsigned)f2bf(v1.y) << 16);
            *(unsigned*)&As[(tt0 + 0) * 40 + 2 * kd] = p0;
            *(unsigned*)&As[(tt0 + 1) * 40 + 2 * kd] = p1;
        }
        *(s16x8*)&Ws[sr * 40 + sc] = w0;
        *(s16x8*)&Ws[(sr + 64) * 40 + sc] = w1;
        *(s16x8*)&Ws[(sr + 128) * 40 + sc] = w2;
        __syncthreads();
        const s16x8 a = *(const s16x8*)&As[(rowhalf * 16 + l16) * 40 + quad * 8];
#pragma unroll
        for (int j = 0; j < 6; ++j) {
            const s16x8 bb = *(const s16x8*)&Ws[((nhalf * 6 + j) * 16 + l16) * 40 + quad * 8];
            acc[j] = __builtin_amdgcn_mfma_f32_16x16x32_bf16(a, bb, acc[j], 0, 0, 0);
        }
    }

    // partial LN stats over this wave's 96 columns
    float sv[4] = {0, 0, 0, 0}, qv[4] = {0, 0, 0, 0};
#pragma unroll
    for (int j = 0; j < 6; ++j)
#pragma unroll
        for (int r = 0; r < 4; ++r) {
            sv[r] += acc[j][r];
            qv[r] = fmaf(acc[j][r], acc[j][r], qv[r]);
        }
#pragma unroll
    for (int r = 0; r < 4; ++r) {
        sv[r] = dpp_add<0xB1>(sv[r]); sv[r] = dpp_add<0x4E>(sv[r]);
        sv[r] = dpp_add<0x124>(sv[r]); sv[r] = dpp_add<0x128>(sv[r]);
        qv[r] = dpp_add<0xB1>(qv[r]); qv[r] = dpp_add<0x4E>(qv[r]);
        qv[r] = dpp_add<0x124>(qv[r]); qv[r] = dpp_add<0x128>(qv[r]);
    }
    __syncthreads();
    if (l16 == 0) {
#pragma unroll
        for (int r = 0; r < 4; ++r) {
            psum[rowhalf * 16 + quad * 4 + r][nhalf][0] = sv[r];
            psum[rowhalf * 16 + quad * 4 + r][nhalf][1] = qv[r];
        }
    }
    __syncthreads();
    float mu[4], rs[4];
#pragma unroll
    for (int r = 0; r < 4; ++r) {
        const int row = rowhalf * 16 + quad * 4 + r;
        const float ts = psum[row][0][0] + psum[row][1][0];
        const float tq = psum[row][0][1] + psum[row][1][1];
        mu[r] = ts * (1.f / 192.f);
        const float var = tq * (1.f / 192.f) - mu[r] * mu[r];
        rs[r] = rsqrtf(var + 1e-5f);
    }
    float gv[6], bv[6];
#pragma unroll
    for (int j = 0; j < 6; ++j) {
        gv[j] = lng[nhalf * 96 + j * 16 + l16];
        bv[j] = lnb[nhalf * 96 + j * 16 + l16];
    }
#pragma unroll
    for (int j = 0; j < 6; ++j)
#pragma unroll
        for (int r = 0; r < 4; ++r) {
            const float v = (acc[j][r] - mu[r]) * rs[r] * gv[j] + bv[j];
            const float ge = 0.5f * v * (1.f + erff(v * 0.70710678118654752f));
            G[(size_t)(m0 + rowhalf * 16 + quad * 4 + r) * RR + nhalf * 96 + j * 16 + l16] =
                f2bf(ge);
        }
}

// ---------------------------------------------------------------------------
// Depthwise causal conv (width 4) + SiLU.  One block per (b, channel) row.
// ---------------------------------------------------------------------------
__global__ __launch_bounds__(256) void conv_silu_kernel(const float* __restrict__ xi_col,
                                                        const float* __restrict__ cw,
                                                        const float* __restrict__ cb,
                                                        float* __restrict__ u_col)
{
    const int row = blockIdx.x;      // b*384 + c
    const int c = row % DI;
    const float* xp = xi_col + (size_t)row * LBATCH;
    float* up = u_col + (size_t)row * LBATCH;
    const float w0 = cw[c * 4 + 0], w1 = cw[c * 4 + 1], w2 = cw[c * 4 + 2], w3 = cw[c * 4 + 3];
    const float bb = cb[c];
    for (int t = threadIdx.x; t < LBATCH; t += 256) {
        const float x3 = xp[t];
        const float x2 = (t >= 1) ? xp[t - 1] : 0.f;
        const float x1 = (t >= 2) ? xp[t - 2] : 0.f;
        const float x0 = (t >= 3) ? xp[t - 3] : 0.f;
        const float v = bb + w0 * x0 + w1 * x1 + w2 * x2 + w3 * x3;
        up[t] = silu_f(v);
    }
}

// ---------------------------------------------------------------------------
// x_dbl = u @ x_proj^T (N=44, K=384), A read col-major (u_col). 32-row tiles
// -> 256 blocks (full GPU). Outputs: dt row-major, BCt interleaved [b][t][32].
// ---------------------------------------------------------------------------
__global__ __launch_bounds__(256) void gemm_xdbl(const float* __restrict__ u_col,
                                                 const float* __restrict__ Wx,
                                                 float* __restrict__ dt,
                                                 float* __restrict__ BCt)
{
    __shared__ float As[16][33];
    __shared__ float Bs[16][68];
    __shared__ float sC[32 * 69];
    const int tid = threadIdx.x;
    const int ty = tid >> 4, tx = tid & 15;
    const int m0 = blockIdx.x * 32;
    const int b = m0 >> 12, tl0 = m0 & 4095;

    float acc[2][4] = {};

    for (int k0 = 0; k0 < DI; k0 += 16) {
        __syncthreads();
        {
            const int m = tid & 31;
            const int kk0 = tid >> 5;  // 0..7
            As[kk0][m] = u_col[((size_t)(b * DI + k0 + kk0)) * LBATCH + tl0 + m];
            As[kk0 + 8][m] = u_col[((size_t)(b * DI + k0 + kk0 + 8)) * LBATCH + tl0 + m];
        }
        if (tid < 176) {
            const int n = tid >> 2;
            const int lk2 = (tid & 3) << 2;
            const float4 wv = *(const float4*)(Wx + (size_t)n * DI + k0 + lk2);
            Bs[lk2 + 0][n] = wv.x; Bs[lk2 + 1][n] = wv.y; Bs[lk2 + 2][n] = wv.z; Bs[lk2 + 3][n] = wv.w;
        }
        __syncthreads();
#pragma unroll
        for (int kk = 0; kk < 16; ++kk) {
            const float a0 = As[kk][ty * 2 + 0];
            const float a1 = As[kk][ty * 2 + 1];
            const float4 b4 = *(const float4*)&Bs[kk][tx << 2];
            const float bb[4] = {b4.x, b4.y, b4.z, b4.w};
#pragma unroll
            for (int j = 0; j < 4; ++j) {
                acc[0][j] = fmaf(a0, bb[j], acc[0][j]);
                acc[1][j] = fmaf(a1, bb[j], acc[1][j]);
            }
        }
    }
    __syncthreads();
#pragma unroll
    for (int i = 0; i < 2; ++i)
#pragma unroll
        for (int j = 0; j < 4; ++j)
            sC[(ty * 2 + i) * 69 + (tx << 2) + j] = acc[i][j];
    __syncthreads();
    for (int idx = tid; idx < 32 * DTRANK; idx += 256) {
        const int t = idx / DTRANK, r = idx - t * DTRANK;
        dt[(size_t)(m0 + t) * DTRANK + r] = sC[t * 69 + r];
    }
    for (int idx = tid; idx < 32 * 32; idx += 256) {
        const int t = idx >> 5, c = idx & 31;
        BCt[((size_t)(b * LBATCH + tl0 + t)) * 32 + c] = sC[t * 69 + DTRANK + c];
    }
}

// ---------------------------------------------------------------------------
// delta = softplus(dt @ dt_proj^T + dt_proj_b), written col-major [b][d][t]
// ---------------------------------------------------------------------------
__global__ __launch_bounds__(256) void delta_kernel(const float* __restrict__ dt,
                                                    const float* __restrict__ dtw,
                                                    const float* __restrict__ dtb,
                                                    float* __restrict__ delta_col)
{
    const int t0g = blockIdx.x * 64;
    const int d0 = blockIdx.y * 64;
    const int b = t0g >> 12, tl0 = t0g & 4095;
    __shared__ float sdt[64][13];
    const int tid = threadIdx.x;
    for (int idx = tid; idx < 64 * DTRANK; idx += 256)
        sdt[idx / DTRANK][idx % DTRANK] = dt[(size_t)t0g * DTRANK + idx];
    __syncthreads();
    const int tl = tid & 63;
    const int dl0 = tid >> 6;
#pragma unroll
    for (int j = 0; j < 16; ++j) {
        const int d = d0 + dl0 + 4 * j;
        float a = dtb[d];
#pragma unroll
        for (int r = 0; r < DTRANK; ++r)
            a = fmaf(sdt[tl][r], dtw[d * DTRANK + r], a);
        delta_col[((size_t)(b * DI + d)) * LBATCH + tl0 + tl] = softplus_f(a);
    }
}

// ---------------------------------------------------------------------------
// Selective scan v6: 512 threads, 128 segments x 32 steps, 4 states/thread.
// Phase 1 stores du = delta*u into LDS (stride 36); phase 2 reads it from LDS
// (u global stream eliminated); u*D recovered as du*rcp(delta). Raw hw
// exp2/rcp. Stride-21 agg arrays; ybuf aliases dead aggA/aggB region.
// ---------------------------------------------------------------------------
__global__ __launch_bounds__(512) void scan_kernel(const float* __restrict__ delta_col,
                                                   const float* __restrict__ u_col,
                                                   const float* __restrict__ BCt,
                                                   const float* __restrict__ z_col,
                                                   const float* __restrict__ A_log,
                                                   const float* __restrict__ Dv,
                                                   float* __restrict__ y_col)
{
    const int bd = blockIdx.x;       // b*384 + d
    const int b = bd / DI;
    const int d = bd - b * DI;
    const int tid = threadIdx.x;
    const int n4 = tid & 3;          // state quad (states 4n4..4n4+3)
    const int s = tid >> 2;          // segment 0..127

    __shared__ float smem[128 * 21 * 3 + 128 * 36];   // 50.7 KB
    float* aggA   = smem;                              // [128*21]
    float* aggB   = smem + 2688;
    float* hst    = smem + 5376;
    float* du_lds = smem + 8064;                       // [128*36]
    float* ybuf   = smem;                              // aliases aggA/aggB (dead after middle)

    const float4 al = *(const float4*)(A_log + d * DSTATE + 4 * n4);
    float An2[4];
    An2[0] = -EXP2F(al.x * LOG2E) * LOG2E;
    An2[1] = -EXP2F(al.y * LOG2E) * LOG2E;
    An2[2] = -EXP2F(al.z * LOG2E) * LOG2E;
    An2[3] = -EXP2F(al.w * LOG2E) * LOG2E;
    const float Dd = Dv[d];

    const int t0 = s * 32;
    const float* dp = delta_col + (size_t)bd * LBATCH + t0;
    const float* up = u_col + (size_t)bd * LBATCH + t0;
    const float* zp = z_col + (size_t)bd * LBATCH + t0;
    const float* bc = BCt + ((size_t)b * LBATCH + t0) * 32 + 4 * n4;

    // ---- phase 1: segment affine aggregate for 4 states; du -> LDS ----
    float Ag[4] = {1.f, 1.f, 1.f, 1.f}, Bg[4] = {0.f, 0.f, 0.f, 0.f};
    {
        const float* bci = bc;
        for (int i = 0; i < 32; i += 4) {
            const float4 d4 = *(const float4*)(dp + i);
            const float4 u4 = *(const float4*)(up + i);
            const float dls[4] = {d4.x, d4.y, d4.z, d4.w};
            const float uus[4] = {u4.x, u4.y, u4.z, u4.w};
            float duv[4];
#pragma unroll
            for (int j = 0; j < 4; ++j) {
                const float4 bm4 = *(const float4*)(bci + j * 32);
                const float du = dls[j] * uus[j];
                duv[j] = du;
                const float bms[4] = {bm4.x, bm4.y, bm4.z, bm4.w};
#pragma unroll
                for (int q = 0; q < 4; ++q) {
                    const float a = EXP2F(dls[j] * An2[q]);
                    Bg[q] = fmaf(a, Bg[q], du * bms[q]);
                    Ag[q] *= a;
                }
            }
            if (n4 == 0)
                *(float4*)&du_lds[s * 36 + i] = make_float4(duv[0], duv[1], duv[2], duv[3]);
            bci += 128;
        }
    }
#pragma unroll
    for (int q = 0; q < 4; ++q) {
        aggA[s * 21 + 4 * n4 + q] = Ag[q];
        aggB[s * 21 + 4 * n4 + q] = Bg[q];
    }
    __syncthreads();

    // ---- middle: per-state inclusive scan over 128 segment aggregates ----
    {
        const int w = tid >> 6;      // wave 0..7 -> states 2w, 2w+1
        const int lane = tid & 63;
#pragma unroll
        for (int r = 0; r < 2; ++r) {
            const int n = w * 2 + r;
            float sA = aggA[lane * 21 + n];
            float sB = aggB[lane * 21 + n];
#pragma unroll
            for (int o = 1; o < 64; o <<= 1) {
                const float pA = __shfl_up(sA, (unsigned)o, 64);
                const float pB = __shfl_up(sB, (unsigned)o, 64);
                if (lane >= o) { sB = fmaf(sA, pB, sB); sA *= pA; }
            }
            const float B0tot = __shfl(sB, 63, 64);
            const float ex0 = __shfl_up(sB, 1, 64);
            hst[lane * 21 + n] = (lane == 0) ? 0.f : ex0;
            float tA = aggA[(64 + lane) * 21 + n];
            float tB = aggB[(64 + lane) * 21 + n];
#pragma unroll
            for (int o = 1; o < 64; o <<= 1) {
                const float pA = __shfl_up(tA, (unsigned)o, 64);
                const float pB = __shfl_up(tB, (unsigned)o, 64);
                if (lane >= o) { tB = fmaf(tA, pB, tB); tA *= pA; }
            }
            const float exA = (lane == 0) ? 1.f : __shfl_up(tA, 1, 64);
            const float exB = (lane == 0) ? 0.f : __shfl_up(tB, 1, 64);
            hst[(64 + lane) * 21 + n] = fmaf(exA, B0tot, exB);
        }
    }
    __syncthreads();

    // ---- phase 2: replay with exact incoming state; du from LDS ----
    float h[4];
#pragma unroll
    for (int q = 0; q < 4; ++q) h[q] = hst[s * 21 + 4 * n4 + q];
    {
        const float* bci = bc;
        for (int i = 0; i < 32; i += 4) {
            const float4 d4 = *(const float4*)(dp + i);
            const float4 z4 = *(const float4*)(zp + i);
            const float4 du4 = *(const float4*)&du_lds[s * 36 + i];
            const float dls[4] = {d4.x, d4.y, d4.z, d4.w};
            const float dus[4] = {du4.x, du4.y, du4.z, du4.w};
            const float zzs[4] = {z4.x, z4.y, z4.z, z4.w};
#pragma unroll
            for (int j = 0; j < 4; ++j) {
                const float4 bm4 = *(const float4*)(bci + j * 32);
                const float4 cm4 = *(const float4*)(bci + j * 32 + 16);
                const float du = dus[j];
                const float bms[4] = {bm4.x, bm4.y, bm4.z, bm4.w};
                const float cms[4] = {cm4.x, cm4.y, cm4.z, cm4.w};
                float p = 0.f;
#pragma unroll
                for (int q = 0; q < 4; ++q) {
                    const float a = EXP2F(dls[j] * An2[q]);
                    h[q] = fmaf(a, h[q], du * bms[q]);
                    p = fmaf(h[q], cms[q], p);
                }
                p = dpp_add<0xB1>(p);   // quad xor1
                p = dpp_add<0x4E>(p);   // quad xor2
                if (n4 == 0) {
                    const float uu = du * RCPF(dls[j]);
                    ybuf[s * 36 + i + j] = (p + uu * Dd) * silu_f(zzs[j]);
                }
            }
            bci += 128;
        }
    }
    __syncthreads();

    // ---- coalesced flush: LDS ybuf -> y_col row ----
    {
        float* yrow = y_col + (size_t)bd * LBATCH;
        for (int idx = tid; idx < 1024; idx += 512) {
            const int ss = idx >> 3, wg = (idx & 7) << 2;
            const float4 v = *(const float4*)&ybuf[ss * 36 + wg];
            *(float4*)(yrow + ss * 32 + wg) = v;
        }
    }
}

// ---------------------------------------------------------------------------
extern "C" void kernel_launch(void* const* d_in, const int* in_sizes, int n_in,
                              void* d_out, int out_size, void* d_ws, size_t ws_size,
                              hipStream_t stream)
{
    const float* x         = (const float*)d_in[0];
    const float* down_w    = (const float*)d_in[1];
    const float* up_w      = (const float*)d_in[2];
    const float* in_proj_w = (const float*)d_in[3];
    const float* conv_w    = (const float*)d_in[4];
    const float* conv_b    = (const float*)d_in[5];
    const float* x_proj_w  = (const float*)d_in[6];
    const float* dt_proj_w = (const float*)d_in[7];
    const float* dt_proj_b = (const float*)d_in[8];
    const float* A_log     = (const float*)d_in[9];
    const float* D_ssm     = (const float*)d_in[10];
    const float* out_proj_w= (const float*)d_in[11];
    const float* ln_g      = (const float*)d_in[12];
    const float* ln_b      = (const float*)d_in[13];
    float* out = (float*)d_out;
    float* ws = (float*)d_ws;

    // fp32 workspace
    float* xi_col    = ws;                        // 2*384*4096 = 3145728
    float* z_col     = xi_col + 3145728;          // 3145728
    float* u_col     = z_col + 3145728;           // 3145728
    float* y_col     = u_col + 3145728;           // 3145728
    float* BCt       = y_col + 3145728;           // 262144
    float* dt        = BCt + 262144;              // 98304
    float* delta_col = xi_col;                    // alias: xi dead after conv
    // bf16 workspace
    unsigned short* xdb = (unsigned short*)(dt + 98304);   // 1572864
    unsigned short* gb  = xdb;                    // alias: xdb dead after gemm2

    // 1. xd = x @ down_w^T  (both operands fp32, converted in staging) -> xdb bf16
    gemm_mfma<0, true, true><<<dim3(3, 128), 256, 0, stream>>>(x, down_w, xdb, nullptr, nullptr, DM, RR);
    // 2. xz = xd @ in_proj^T -> xi_col, z_col (fp32 col-major); W cvt in staging
    gemm_mfma<1, false, true><<<dim3(12, 128), 256, 0, stream>>>(xdb, in_proj_w, xi_col, z_col, nullptr, RR, 2 * DI);
    // 3. depthwise conv4 + silu -> u_col
    conv_silu_kernel<<<768, 256, 0, stream>>>(xi_col, conv_w, conv_b, u_col);
    // 4. x_dbl = u @ x_proj^T -> dt, BCt  (32-row tiles, 256 blocks)
    gemm_xdbl<<<256, 256, 0, stream>>>(u_col, x_proj_w, dt, BCt);
    // 5. delta = softplus(dt @ dt_proj^T + b) -> delta_col (aliases xi_col)
    delta_kernel<<<dim3(128, 6), 256, 0, stream>>>(dt, dt_proj_w, dt_proj_b, delta_col);
    // 6. selective scan v6 + gating -> y_col
    scan_kernel<<<768, 512, 0, stream>>>(delta_col, u_col, BCt, z_col, A_log, D_ssm, y_col);
    // 7. m = y @ out_proj^T + LN + GELU (32-row tiles, 256 blocks) -> gb
    gemm_ln_mfma<<<256, 256, 0, stream>>>(y_col, out_proj_w, ln_g, ln_b, gb);
    // 8. out = x + g @ up_w^T (fp32 store); W cvt in staging
    gemm_mfma<2, false, true><<<dim3(12, 128), 256, 0, stream>>>(gb, up_w, out, nullptr, x, RR, DM);
}

// Round 9
// 247.745 us; speedup vs baseline: 1.2463x; 1.0685x over previous
//
#include <hip/hip_runtime.h>
#include <math.h>

// Problem constants
#define LBATCH 4096  // tokens per mamba batch (b=2)
#define DM 768
#define RR 192
#define DI 384
#define DSTATE 16
#define DTRANK 12

typedef __attribute__((ext_vector_type(8))) short s16x8;   // 8 bf16 in 4 VGPRs
typedef __attribute__((ext_vector_type(4))) float f32x4;   // MFMA accumulator

#define EXP2F(x) __builtin_amdgcn_exp2f(x)
#define LOG2F(x) __builtin_amdgcn_logf(x)
#define RCPF(x)  __builtin_amdgcn_rcpf(x)
#define LOG2E 1.44269504f

__device__ __forceinline__ float silu_f(float x) {
    return x * RCPF(1.f + EXP2F(-LOG2E * x));
}
__device__ __forceinline__ float softplus_f(float x) {
    return 0.69314718056f * LOG2F(1.f + EXP2F(LOG2E * x));
}

__device__ __forceinline__ unsigned short f2bf(float f) {   // RNE fp32->bf16
    unsigned u = __float_as_uint(f);
    u += 0x7FFFu + ((u >> 16) & 1u);
    return (unsigned short)(u >> 16);
}
__device__ __forceinline__ float bf2f(unsigned short u) {
    return __uint_as_float((unsigned)u << 16);
}

// load 8 consecutive fp32 and pack to 8 bf16 (4 VGPRs)
__device__ __forceinline__ s16x8 pack_bf8(const float* __restrict__ p) {
    const float4 f0 = *(const float4*)p;
    const float4 f1 = *(const float4*)(p + 4);
    union { s16x8 v; unsigned short u[8]; } pk;
    pk.u[0] = f2bf(f0.x); pk.u[1] = f2bf(f0.y); pk.u[2] = f2bf(f0.z); pk.u[3] = f2bf(f0.w);
    pk.u[4] = f2bf(f1.x); pk.u[5] = f2bf(f1.y); pk.u[6] = f2bf(f1.z); pk.u[7] = f2bf(f1.w);
    return pk.v;
}

// DPP partial sums across aligned lane groups (VALU pipe, no LDS).
template <int CTRL>
__device__ __forceinline__ float dpp_add(float x) {
    const int y = __builtin_amdgcn_update_dpp(0, __float_as_int(x), CTRL, 0xF, 0xF, false);
    return x + __int_as_float(y);
}

// ---------------------------------------------------------------------------
// bf16 MFMA GEMM: C(M,N) = A(M,K) @ W(N,K)^T, 64x64 tile, 4 waves (wave: 64Mx16N)
// CVTA: A fp32 -> bf16 in staging.  CVTW: W fp32 -> bf16 in staging.
// MODE 0: store C as bf16 row-major
// MODE 1: transposed split store -> BF16 xi[b][ch][t] / z[b][ch][t]
// MODE 2: store fp32 C = acc + X (residual), row-major
// ---------------------------------------------------------------------------
template <int MODE, bool CVTA, bool CVTW>
__global__ __launch_bounds__(256) void gemm_mfma(const void* __restrict__ Araw,
                                                 const void* __restrict__ Wraw,
                                                 void* __restrict__ C0,
                                                 void* __restrict__ C1,
                                                 const float* __restrict__ X,
                                                 int K, int N)
{
    __shared__ unsigned short As[64 * 40];
    __shared__ unsigned short Ws[64 * 40];
    __shared__ float sC[(MODE == 1) ? 64 * 65 : 1];

    const int tid = threadIdx.x;
    const int wave = tid >> 6, lane = tid & 63;
    const int quad = lane >> 4, l16 = lane & 15;
    const int m0 = blockIdx.y * 64, n0 = blockIdx.x * 64;

    f32x4 acc[4] = {};

    const int sr = tid >> 2;          // staging row 0..63
    const int sc = (tid & 3) * 8;     // staging k-offset

    for (int k0 = 0; k0 < K; k0 += 32) {
        s16x8 av, wv;
        if (CVTA) {
            av = pack_bf8((const float*)Araw + (size_t)(m0 + sr) * K + k0 + sc);
        } else {
            av = *(const s16x8*)((const unsigned short*)Araw + (size_t)(m0 + sr) * K + k0 + sc);
        }
        if (CVTW) {
            wv = pack_bf8((const float*)Wraw + (size_t)(n0 + sr) * K + k0 + sc);
        } else {
            wv = *(const s16x8*)((const unsigned short*)Wraw + (size_t)(n0 + sr) * K + k0 + sc);
        }
        __syncthreads();
        *(s16x8*)&As[sr * 40 + sc] = av;
        *(s16x8*)&Ws[sr * 40 + sc] = wv;
        __syncthreads();
        const s16x8 b = *(const s16x8*)&Ws[(wave * 16 + l16) * 40 + quad * 8];
#pragma unroll
        for (int mi = 0; mi < 4; ++mi) {
            const s16x8 a = *(const s16x8*)&As[(mi * 16 + l16) * 40 + quad * 8];
            acc[mi] = __builtin_amdgcn_mfma_f32_16x16x32_bf16(a, b, acc[mi], 0, 0, 0);
        }
    }

    if (MODE == 0) {
        unsigned short* Crow = (unsigned short*)C0;
#pragma unroll
        for (int mi = 0; mi < 4; ++mi)
#pragma unroll
            for (int r = 0; r < 4; ++r)
                Crow[(size_t)(m0 + mi * 16 + quad * 4 + r) * N + n0 + wave * 16 + l16] =
                    f2bf(acc[mi][r]);
    } else if (MODE == 2) {
        float* Co = (float*)C0;
#pragma unroll
        for (int mi = 0; mi < 4; ++mi)
#pragma unroll
            for (int r = 0; r < 4; ++r) {
                const size_t off =
                    (size_t)(m0 + mi * 16 + quad * 4 + r) * N + n0 + wave * 16 + l16;
                Co[off] = acc[mi][r] + X[off];
            }
    } else {
#pragma unroll
        for (int mi = 0; mi < 4; ++mi)
#pragma unroll
            for (int r = 0; r < 4; ++r)
                sC[(wave * 16 + l16) * 65 + mi * 16 + quad * 4 + r] = acc[mi][r];
        __syncthreads();
        const int b = m0 >> 12, tl0 = m0 & 4095;
        for (int idx = tid; idx < 1024; idx += 256) {
            const int nn = idx >> 4, t4 = (idx & 15) << 2;
            ushort4 o;
            o.x = f2bf(sC[nn * 65 + t4]);
            o.y = f2bf(sC[nn * 65 + t4 + 1]);
            o.z = f2bf(sC[nn * 65 + t4 + 2]);
            o.w = f2bf(sC[nn * 65 + t4 + 3]);
            const int gch = n0 + nn;
            unsigned short* dst = (gch < DI)
                ? (unsigned short*)C0 + ((size_t)(b * DI + gch)) * LBATCH
                : (unsigned short*)C1 + ((size_t)(b * DI + gch - DI)) * LBATCH;
            *(ushort4*)(dst + tl0 + t4) = o;
        }
    }
}

// ---------------------------------------------------------------------------
// m = y @ out_proj^T (bf16 MFMA, K=384, N=192) + LayerNorm + exact GELU -> bf16 G.
// y is BF16 col-major [b][d][t]: staging is a pure 2-ushort pack (no cvt).
// 32-row tiles, 256 blocks. 4 waves: rowhalf = wave>>1, nhalf = wave&1.
// ---------------------------------------------------------------------------
__global__ __launch_bounds__(256) void gemm_ln_mfma(const unsigned short* __restrict__ ycol,
                                                    const float* __restrict__ Wf,
                                                    const float* __restrict__ lng,
                                                    const float* __restrict__ lnb,
                                                    unsigned short* __restrict__ G)
{
    __shared__ unsigned short As[32 * 40];
    __shared__ unsigned short Ws[192 * 40];
    __shared__ float psum[32][2][2];   // [row][nhalf][s|q]
    const int tid = threadIdx.x;
    const int wave = tid >> 6, lane = tid & 63;
    const int quad = lane >> 4, l16 = lane & 15;
    const int rowhalf = wave >> 1, nhalf = wave & 1;
    const int m0 = blockIdx.x * 32;
    const int b = m0 >> 12, tl0 = m0 & 4095;

    f32x4 acc[6] = {};
    const int sr = tid >> 2, sc = (tid & 3) * 8;   // W staging
    const int kd = tid >> 4, tt0 = (tid & 15) * 2; // A staging: d-pair 2kd, tokens tt0,tt0+1

    for (int k0 = 0; k0 < DI; k0 += 32) {
        const unsigned short* y0 =
            ycol + ((size_t)(b * DI + k0 + 2 * kd)) * LBATCH + tl0 + tt0;
        const ushort2 v0 = *(const ushort2*)y0;            // d = k0+2kd
        const ushort2 v1 = *(const ushort2*)(y0 + LBATCH); // d = k0+2kd+1
        const float* wp = Wf + (size_t)sr * DI + k0 + sc;
        const s16x8 w0 = pack_bf8(wp);
        const s16x8 w1 = pack_bf8(wp + (size_t)64 * DI);
        const s16x8 w2 = pack_bf8(wp + (size_t)128 * DI);
        __syncthreads();
        {
            const unsigned p0 = (unsigned)v0.x | ((unsigned)v1.x << 16);
            const unsigned p1 = (unsigned)v0.y | ((unsigned)v1.y << 16);
            *(unsigned*)&As[(tt0 + 0) * 40 + 2 * kd] = p0;
            *(unsigned*)&As[(tt0 + 1) * 40 + 2 * kd] = p1;
        }
        *(s16x8*)&Ws[sr * 40 + sc] = w0;
        *(s16x8*)&Ws[(sr + 64) * 40 + sc] = w1;
        *(s16x8*)&Ws[(sr + 128) * 40 + sc] = w2;
        __syncthreads();
        const s16x8 a = *(const s16x8*)&As[(rowhalf * 16 + l16) * 40 + quad * 8];
#pragma unroll
        for (int j = 0; j < 6; ++j) {
            const s16x8 bb = *(const s16x8*)&Ws[((nhalf * 6 + j) * 16 + l16) * 40 + quad * 8];
            acc[j] = __builtin_amdgcn_mfma_f32_16x16x32_bf16(a, bb, acc[j], 0, 0, 0);
        }
    }

    float sv[4] = {0, 0, 0, 0}, qv[4] = {0, 0, 0, 0};
#pragma unroll
    for (int j = 0; j < 6; ++j)
#pragma unroll
        for (int r = 0; r < 4; ++r) {
            sv[r] += acc[j][r];
            qv[r] = fmaf(acc[j][r], acc[j][r], qv[r]);
        }
#pragma unroll
    for (int r = 0; r < 4; ++r) {
        sv[r] = dpp_add<0xB1>(sv[r]); sv[r] = dpp_add<0x4E>(sv[r]);
        sv[r] = dpp_add<0x124>(sv[r]); sv[r] = dpp_add<0x128>(sv[r]);
        qv[r] = dpp_add<0xB1>(qv[r]); qv[r] = dpp_add<0x4E>(qv[r]);
        qv[r] = dpp_add<0x124>(qv[r]); qv[r] = dpp_add<0x128>(qv[r]);
    }
    __syncthreads();
    if (l16 == 0) {
#pragma unroll
        for (int r = 0; r < 4; ++r) {
            psum[rowhalf * 16 + quad * 4 + r][nhalf][0] = sv[r];
            psum[rowhalf * 16 + quad * 4 + r][nhalf][1] = qv[r];
        }
    }
    __syncthreads();
    float mu[4], rs[4];
#pragma unroll
    for (int r = 0; r < 4; ++r) {
        const int row = rowhalf * 16 + quad * 4 + r;
        const float ts = psum[row][0][0] + psum[row][1][0];
        const float tq = psum[row][0][1] + psum[row][1][1];
        mu[r] = ts * (1.f / 192.f);
        const float var = tq * (1.f / 192.f) - mu[r] * mu[r];
        rs[r] = rsqrtf(var + 1e-5f);
    }
    float gv[6], bv[6];
#pragma unroll
    for (int j = 0; j < 6; ++j) {
        gv[j] = lng[nhalf * 96 + j * 16 + l16];
        bv[j] = lnb[nhalf * 96 + j * 16 + l16];
    }
#pragma unroll
    for (int j = 0; j < 6; ++j)
#pragma unroll
        for (int r = 0; r < 4; ++r) {
            const float v = (acc[j][r] - mu[r]) * rs[r] * gv[j] + bv[j];
            const float ge = 0.5f * v * (1.f + erff(v * 0.70710678118654752f));
            G[(size_t)(m0 + rowhalf * 16 + quad * 4 + r) * RR + nhalf * 96 + j * 16 + l16] =
                f2bf(ge);
        }
}

// ---------------------------------------------------------------------------
// Depthwise causal conv (width 4) + SiLU, bf16 in/out. One block per (b,c) row.
// ---------------------------------------------------------------------------
__global__ __launch_bounds__(256) void conv_silu_kernel(const unsigned short* __restrict__ xi,
                                                        const float* __restrict__ cw,
                                                        const float* __restrict__ cb,
                                                        unsigned short* __restrict__ u)
{
    const int row = blockIdx.x;      // b*384 + c
    const int c = row % DI;
    const unsigned short* xp = xi + (size_t)row * LBATCH;
    unsigned short* up = u + (size_t)row * LBATCH;
    const float w0 = cw[c * 4 + 0], w1 = cw[c * 4 + 1], w2 = cw[c * 4 + 2], w3 = cw[c * 4 + 3];
    const float bb = cb[c];
    for (int t4 = threadIdx.x * 4; t4 < LBATCH; t4 += 1024) {
        const ushort4 xv = *(const ushort4*)(xp + t4);
        const float x0 = bf2f(xv.x), x1 = bf2f(xv.y), x2 = bf2f(xv.z), x3 = bf2f(xv.w);
        const float h0 = (t4 >= 1) ? bf2f(xp[t4 - 1]) : 0.f;
        const float h1 = (t4 >= 2) ? bf2f(xp[t4 - 2]) : 0.f;
        const float h2 = (t4 >= 3) ? bf2f(xp[t4 - 3]) : 0.f;
        ushort4 o;
        o.x = f2bf(silu_f(bb + w0 * h2 + w1 * h1 + w2 * h0 + w3 * x0));
        o.y = f2bf(silu_f(bb + w0 * h1 + w1 * h0 + w2 * x0 + w3 * x1));
        o.z = f2bf(silu_f(bb + w0 * h0 + w1 * x0 + w2 * x1 + w3 * x2));
        o.w = f2bf(silu_f(bb + w0 * x0 + w1 * x1 + w2 * x2 + w3 * x3));
        *(ushort4*)(up + t4) = o;
    }
}

// ---------------------------------------------------------------------------
// x_dbl = u @ x_proj^T (N=44, K=384), A read col-major (bf16 u). 32-row tiles
// -> 256 blocks. Outputs: dt row-major fp32, BCt interleaved [b][t][32] fp32.
// ---------------------------------------------------------------------------
__global__ __launch_bounds__(256) void gemm_xdbl(const unsigned short* __restrict__ u_col,
                                                 const float* __restrict__ Wx,
                                                 float* __restrict__ dt,
                                                 float* __restrict__ BCt)
{
    __shared__ float As[16][33];
    __shared__ float Bs[16][68];
    __shared__ float sC[32 * 69];
    const int tid = threadIdx.x;
    const int ty = tid >> 4, tx = tid & 15;
    const int m0 = blockIdx.x * 32;
    const int b = m0 >> 12, tl0 = m0 & 4095;

    float acc[2][4] = {};

    for (int k0 = 0; k0 < DI; k0 += 16) {
        __syncthreads();
        {
            const int m = tid & 31;
            const int kk0 = tid >> 5;  // 0..7
            As[kk0][m] = bf2f(u_col[((size_t)(b * DI + k0 + kk0)) * LBATCH + tl0 + m]);
            As[kk0 + 8][m] = bf2f(u_col[((size_t)(b * DI + k0 + kk0 + 8)) * LBATCH + tl0 + m]);
        }
        if (tid < 176) {
            const int n = tid >> 2;
            const int lk2 = (tid & 3) << 2;
            const float4 wv = *(const float4*)(Wx + (size_t)n * DI + k0 + lk2);
            Bs[lk2 + 0][n] = wv.x; Bs[lk2 + 1][n] = wv.y; Bs[lk2 + 2][n] = wv.z; Bs[lk2 + 3][n] = wv.w;
        }
        __syncthreads();
#pragma unroll
        for (int kk = 0; kk < 16; ++kk) {
            const float a0 = As[kk][ty * 2 + 0];
            const float a1 = As[kk][ty * 2 + 1];
            const float4 b4 = *(const float4*)&Bs[kk][tx << 2];
            const float bb[4] = {b4.x, b4.y, b4.z, b4.w};
#pragma unroll
            for (int j = 0; j < 4; ++j) {
                acc[0][j] = fmaf(a0, bb[j], acc[0][j]);
                acc[1][j] = fmaf(a1, bb[j], acc[1][j]);
            }
        }
    }
    __syncthreads();
#pragma unroll
    for (int i = 0; i < 2; ++i)
#pragma unroll
        for (int j = 0; j < 4; ++j)
            sC[(ty * 2 + i) * 69 + (tx << 2) + j] = acc[i][j];
    __syncthreads();
    for (int idx = tid; idx < 32 * DTRANK; idx += 256) {
        const int t = idx / DTRANK, r = idx - t * DTRANK;
        dt[(size_t)(m0 + t) * DTRANK + r] = sC[t * 69 + r];
    }
    for (int idx = tid; idx < 32 * 32; idx += 256) {
        const int t = idx >> 5, c = idx & 31;
        BCt[((size_t)(b * LBATCH + tl0 + t)) * 32 + c] = sC[t * 69 + DTRANK + c];
    }
}

// ---------------------------------------------------------------------------
// delta = softplus(dt @ dt_proj^T + dt_proj_b), written col-major [b][d][t]
// ---------------------------------------------------------------------------
__global__ __launch_bounds__(256) void delta_kernel(const float* __restrict__ dt,
                                                    const float* __restrict__ dtw,
                                                    const float* __restrict__ dtb,
                                                    float* __restrict__ delta_col)
{
    const int t0g = blockIdx.x * 64;
    const int d0 = blockIdx.y * 64;
    const int b = t0g >> 12, tl0 = t0g & 4095;
    __shared__ float sdt[64][13];
    const int tid = threadIdx.x;
    for (int idx = tid; idx < 64 * DTRANK; idx += 256)
        sdt[idx / DTRANK][idx % DTRANK] = dt[(size_t)t0g * DTRANK + idx];
    __syncthreads();
    const int tl = tid & 63;
    const int dl0 = tid >> 6;
#pragma unroll
    for (int j = 0; j < 16; ++j) {
        const int d = d0 + dl0 + 4 * j;
        float a = dtb[d];
#pragma unroll
        for (int r = 0; r < DTRANK; ++r)
            a = fmaf(sdt[tl][r], dtw[d * DTRANK + r], a);
        delta_col[((size_t)(b * DI + d)) * LBATCH + tl0 + tl] = softplus_f(a);
    }
}

// ---------------------------------------------------------------------------
// Selective scan v7: v5 loop structure (low VGPR), raw exp2, bf16 u/z/y.
// 512 threads, 128 segments x 32 steps, 4 states/thread; stride-21 agg arrays;
// ybuf (stride 36) aliases dead aggA/aggB; coalesced bf16 y flush.
// ---------------------------------------------------------------------------
__global__ __launch_bounds__(512) void scan_kernel(const float* __restrict__ delta_col,
                                                   const unsigned short* __restrict__ u_col,
                                                   const float* __restrict__ BCt,
                                                   const unsigned short* __restrict__ z_col,
                                                   const float* __restrict__ A_log,
                                                   const float* __restrict__ Dv,
                                                   unsigned short* __restrict__ y_col)
{
    const int bd = blockIdx.x;       // b*384 + d
    const int b = bd / DI;
    const int d = bd - b * DI;
    const int tid = threadIdx.x;
    const int n4 = tid & 3;          // state quad (states 4n4..4n4+3)
    const int s = tid >> 2;          // segment 0..127

    __shared__ float smem[128 * 21 * 3];          // 32.25 KB
    float* aggA = smem;
    float* aggB = smem + 2688;
    float* hst  = smem + 5376;
    float* ybuf = smem;                            // aliases aggA/aggB after middle

    const float4 al = *(const float4*)(A_log + d * DSTATE + 4 * n4);
    float An2[4];
    An2[0] = -EXP2F(al.x * LOG2E) * LOG2E;
    An2[1] = -EXP2F(al.y * LOG2E) * LOG2E;
    An2[2] = -EXP2F(al.z * LOG2E) * LOG2E;
    An2[3] = -EXP2F(al.w * LOG2E) * LOG2E;
    const float Dd = Dv[d];

    const int t0 = s * 32;
    const float* dp = delta_col + (size_t)bd * LBATCH + t0;
    const unsigned short* up = u_col + (size_t)bd * LBATCH + t0;
    const unsigned short* zp = z_col + (size_t)bd * LBATCH + t0;
    const float* bc = BCt + ((size_t)b * LBATCH + t0) * 32 + 4 * n4;

    // ---- phase 1: segment affine aggregate for 4 states ----
    float Ag[4] = {1.f, 1.f, 1.f, 1.f}, Bg[4] = {0.f, 0.f, 0.f, 0.f};
    {
        const float* bci = bc;
        for (int i = 0; i < 32; i += 4) {
            const float4 d4 = *(const float4*)(dp + i);
            const ushort4 uv = *(const ushort4*)(up + i);
            const float dls[4] = {d4.x, d4.y, d4.z, d4.w};
            const float uus[4] = {bf2f(uv.x), bf2f(uv.y), bf2f(uv.z), bf2f(uv.w)};
#pragma unroll
            for (int j = 0; j < 4; ++j) {
                const float4 bm4 = *(const float4*)(bci + j * 32);
                const float du = dls[j] * uus[j];
                const float bms[4] = {bm4.x, bm4.y, bm4.z, bm4.w};
#pragma unroll
                for (int q = 0; q < 4; ++q) {
                    const float a = EXP2F(dls[j] * An2[q]);
                    Bg[q] = fmaf(a, Bg[q], du * bms[q]);
                    Ag[q] *= a;
                }
            }
            bci += 128;
        }
    }
#pragma unroll
    for (int q = 0; q < 4; ++q) {
        aggA[s * 21 + 4 * n4 + q] = Ag[q];
        aggB[s * 21 + 4 * n4 + q] = Bg[q];
    }
    __syncthreads();

    // ---- middle: per-state inclusive scan over 128 segment aggregates ----
    {
        const int w = tid >> 6;      // wave 0..7 -> states 2w, 2w+1
        const int lane = tid & 63;
#pragma unroll
        for (int r = 0; r < 2; ++r) {
            const int n = w * 2 + r;
            float sA = aggA[lane * 21 + n];
            float sB = aggB[lane * 21 + n];
#pragma unroll
            for (int o = 1; o < 64; o <<= 1) {
                const float pA = __shfl_up(sA, (unsigned)o, 64);
                const float pB = __shfl_up(sB, (unsigned)o, 64);
                if (lane >= o) { sB = fmaf(sA, pB, sB); sA *= pA; }
            }
            const float B0tot = __shfl(sB, 63, 64);
            const float ex0 = __shfl_up(sB, 1, 64);
            hst[lane * 21 + n] = (lane == 0) ? 0.f : ex0;
            float tA = aggA[(64 + lane) * 21 + n];
            float tB = aggB[(64 + lane) * 21 + n];
#pragma unroll
            for (int o = 1; o < 64; o <<= 1) {
                const float pA = __shfl_up(tA, (unsigned)o, 64);
                const float pB = __shfl_up(tB, (unsigned)o, 64);
                if (lane >= o) { tB = fmaf(tA, pB, tB); tA *= pA; }
            }
            const float exA = (lane == 0) ? 1.f : __shfl_up(tA, 1, 64);
            const float exB = (lane == 0) ? 0.f : __shfl_up(tB, 1, 64);
            hst[(64 + lane) * 21 + n] = fmaf(exA, B0tot, exB);
        }
    }
    __syncthreads();

    // ---- phase 2: replay with exact incoming state ----
    float h[4];
#pragma unroll
    for (int q = 0; q < 4; ++q) h[q] = hst[s * 21 + 4 * n4 + q];
    {
        const float* bci = bc;
        for (int i = 0; i < 32; i += 4) {
            const float4 d4 = *(const float4*)(dp + i);
            const ushort4 uv = *(const ushort4*)(up + i);
            const ushort4 zv = *(const ushort4*)(zp + i);
            const float dls[4] = {d4.x, d4.y, d4.z, d4.w};
            const float uus[4] = {bf2f(uv.x), bf2f(uv.y), bf2f(uv.z), bf2f(uv.w)};
            const float zzs[4] = {bf2f(zv.x), bf2f(zv.y), bf2f(zv.z), bf2f(zv.w)};
#pragma unroll
            for (int j = 0; j < 4; ++j) {
                const float4 bm4 = *(const float4*)(bci + j * 32);
                const float4 cm4 = *(const float4*)(bci + j * 32 + 16);
                const float du = dls[j] * uus[j];
                const float bms[4] = {bm4.x, bm4.y, bm4.z, bm4.w};
                const float cms[4] = {cm4.x, cm4.y, cm4.z, cm4.w};
                float p = 0.f;
#pragma unroll
                for (int q = 0; q < 4; ++q) {
                    const float a = EXP2F(dls[j] * An2[q]);
                    h[q] = fmaf(a, h[q], du * bms[q]);
                    p = fmaf(h[q], cms[q], p);
                }
                p = dpp_add<0xB1>(p);   // quad xor1
                p = dpp_add<0x4E>(p);   // quad xor2
                if (n4 == 0)
                    ybuf[s * 36 + i + j] = (p + uus[j] * Dd) * silu_f(zzs[j]);
            }
            bci += 128;
        }
    }
    __syncthreads();

    // ---- coalesced flush: LDS ybuf -> bf16 y_col row ----
    {
        unsigned short* yrow = y_col + (size_t)bd * LBATCH;
        for (int idx = tid; idx < 1024; idx += 512) {
            const int ss = idx >> 3, wg = (idx & 7) << 2;
            const float4 v = *(const float4*)&ybuf[ss * 36 + wg];
            ushort4 o;
            o.x = f2bf(v.x); o.y = f2bf(v.y); o.z = f2bf(v.z); o.w = f2bf(v.w);
            *(ushort4*)(yrow + ss * 32 + wg) = o;
        }
    }
}

// ---------------------------------------------------------------------------
extern "C" void kernel_launch(void* const* d_in, const int* in_sizes, int n_in,
                              void* d_out, int out_size, void* d_ws, size_t ws_size,
                              hipStream_t stream)
{
    const float* x         = (const float*)d_in[0];
    const float* down_w    = (const float*)d_in[1];
    const float* up_w      = (const float*)d_in[2];
    const float* in_proj_w = (const float*)d_in[3];
    const float* conv_w    = (const float*)d_in[4];
    const float* conv_b    = (const float*)d_in[5];
    const float* x_proj_w  = (const float*)d_in[6];
    const float* dt_proj_w = (const float*)d_in[7];
    const float* dt_proj_b = (const float*)d_in[8];
    const float* A_log     = (const float*)d_in[9];
    const float* D_ssm     = (const float*)d_in[10];
    const float* out_proj_w= (const float*)d_in[11];
    const float* ln_g      = (const float*)d_in[12];
    const float* ln_b      = (const float*)d_in[13];
    float* out = (float*)d_out;
    float* ws = (float*)d_ws;

    // fp32 workspace
    float* delta_col = ws;                        // 3145728
    float* BCt       = delta_col + 3145728;       // 262144
    float* dt        = BCt + 262144;              // 98304
    // bf16 workspace
    unsigned short* xi_b = (unsigned short*)(dt + 98304);  // 3145728
    unsigned short* z_b  = xi_b + 3145728;        // 3145728
    unsigned short* u_b  = z_b + 3145728;         // 3145728
    unsigned short* y_b  = u_b + 3145728;         // 3145728
    unsigned short* xdb  = y_b + 3145728;         // 1572864
    unsigned short* gb   = xdb;                   // alias: xdb dead after gemm2

    // 1. xd = x @ down_w^T (fp32 A+W cvt in staging) -> xdb bf16 row-major
    gemm_mfma<0, true, true><<<dim3(3, 128), 256, 0, stream>>>(x, down_w, xdb, nullptr, nullptr, DM, RR);
    // 2. xz = xd @ in_proj^T -> bf16 xi_b, z_b (col-major); W cvt in staging
    gemm_mfma<1, false, true><<<dim3(12, 128), 256, 0, stream>>>(xdb, in_proj_w, xi_b, z_b, nullptr, RR, 2 * DI);
    // 3. depthwise conv4 + silu (bf16 -> bf16) -> u_b
    conv_silu_kernel<<<768, 256, 0, stream>>>(xi_b, conv_w, conv_b, u_b);
    // 4. x_dbl = u @ x_proj^T -> dt, BCt  (32-row tiles, 256 blocks)
    gemm_xdbl<<<256, 256, 0, stream>>>(u_b, x_proj_w, dt, BCt);
    // 5. delta = softplus(dt @ dt_proj^T + b) -> delta_col
    delta_kernel<<<dim3(128, 6), 256, 0, stream>>>(dt, dt_proj_w, dt_proj_b, delta_col);
    // 6. selective scan v7 + gating -> y_b (bf16)
    scan_kernel<<<768, 512, 0, stream>>>(delta_col, u_b, BCt, z_b, A_log, D_ssm, y_b);
    // 7. m = y @ out_proj^T + LN + GELU (32-row tiles, 256 blocks) -> gb
    gemm_ln_mfma<<<256, 256, 0, stream>>>(y_b, out_proj_w, ln_g, ln_b, gb);
    // 8. out = x + g @ up_w^T (fp32 store); W cvt in staging
    gemm_mfma<2, false, true><<<dim3(12, 128), 256, 0, stream>>>(gb, up_w, out, nullptr, x, RR, DM);
}